// Round 8
// baseline (372.298 us; speedup 1.0000x reference)
//
#include <hip/hip_runtime.h>
#include <hip/hip_bf16.h>

// Non-local block, B=8 C=512 H=W=64, IC=256, N2=HW=4096, N=2048 (folded).
//
// Round-11 (resubmit; round-7 bench was an infra failure, kernel audited):
// gemmG_f FUSED into conv_ptf -> conv_ptg. x-blocks compute theta
// AND G from ONE staging of the x tile (G via swapped-operand MFMA on the
// same LDS tiles; wg staged in a 3rd buffer pair by the weight waves).
// Eliminates the second full read of x (the ~1.1 TB/s strided-row pattern)
// and one ~50us dispatch. launch_bounds(512,2), 80KB LDS.
// Rest identical to round 10.

typedef __attribute__((ext_vector_type(8))) short short8;
typedef __attribute__((ext_vector_type(4))) short short4v;
typedef __attribute__((ext_vector_type(4))) float f32x4;

__device__ __forceinline__ short f2bf(float f) {
  union { __hip_bfloat16 h; short s; } u; u.h = __float2bfloat16(f); return u.s;
}
__device__ __forceinline__ float bf2f(short s) {
  union { short s; __hip_bfloat16 h; } u; u.s = s; return __bfloat162float(u.h);
}

__device__ __forceinline__ void async_ld16(const void* g, void* l) {
  __builtin_amdgcn_global_load_lds(
      (const __attribute__((address_space(1))) unsigned int*)(unsigned long long)g,
      (__attribute__((address_space(3))) unsigned int*)(unsigned int)(unsigned long long)l,
      16, 0, 0);
}

// swizzled b128 fragment read from a [row][32-short] tile whose 16B-unit u
// holds global chunk u ^ ((row>>2)&3)
__device__ __forceinline__ short8 frag_sw(const short* Ds, int row, int q8)
{
  return *(const short8*)&Ds[row * 32 + (((q8 >> 3) ^ ((row >> 2) & 3)) << 3)];
}

// ---------------- OV GEMM v2: dbuf, single barrier, swizzled ---------------
// OVT[b][n][c] = sum_m E[n][m]*G''[c][m]. 512 blocks; XCD-local slab map.
__global__ __launch_bounds__(512, 4)
void ov_k(const short* __restrict__ Eg, const short* __restrict__ Gg,
          short* __restrict__ Cg)
{
  const int L = blockIdx.x;
  const int xcd = L & 7, k = L >> 3;
  const int slab = xcd + ((k >> 2) << 3);   // 0..127
  const int bz = slab >> 4, by = slab & 15, bx = k & 3;

  __shared__ __align__(16) short As[2][128 * 32];
  __shared__ __align__(16) short Bs[2][128 * 32];
  const short* A = Eg + ((long)bz << 22);
  const short* B = Gg + ((long)bz << 20);
  const int m0 = by * 128;
  const int n0 = bx * 128;
  const int t = threadIdx.x;
  const int wv = t >> 6, ln = t & 63;
  const int wr = wv >> 1, wc = wv & 1;
  const int fr = ln & 15, q8 = (ln >> 4) * 8;
  const int rowA = t >> 2;
  const int kcs = ((t & 3) ^ ((t >> 4) & 3)) * 8;   // inverse-swizzled source chunk

  f32x4 acc[2][4];
  #pragma unroll
  for (int i = 0; i < 2; i++)
    #pragma unroll
    for (int j = 0; j < 4; j++)
      #pragma unroll
      for (int r = 0; r < 4; r++) acc[i][j][r] = 0.f;

  async_ld16(A + (long)(m0 + rowA) * 2048 + kcs, &As[0][0] + wv * 512);
  async_ld16(B + (long)(n0 + rowA) * 2048 + kcs, &Bs[0][0] + wv * 512);
  __syncthreads();

  for (int kt = 1; kt < 64; kt++) {
    const int cur = (kt - 1) & 1, nxt = kt & 1;
    async_ld16(A + (long)(m0 + rowA) * 2048 + kt * 32 + kcs, &As[nxt][0] + wv * 512);
    async_ld16(B + (long)(n0 + rowA) * 2048 + kt * 32 + kcs, &Bs[nxt][0] + wv * 512);
    short8 af[2], bfr[4];
    #pragma unroll
    for (int mi = 0; mi < 2; mi++) af[mi] = frag_sw(&As[cur][0], wr * 32 + mi * 16 + fr, q8);
    #pragma unroll
    for (int ni = 0; ni < 4; ni++) bfr[ni] = frag_sw(&Bs[cur][0], wc * 64 + ni * 16 + fr, q8);
    #pragma unroll
    for (int mi = 0; mi < 2; mi++)
      #pragma unroll
      for (int ni = 0; ni < 4; ni++)
        acc[mi][ni] = __builtin_amdgcn_mfma_f32_16x16x32_bf16(af[mi], bfr[ni], acc[mi][ni], 0, 0, 0);
    __syncthreads();
  }
  {
    short8 af[2], bfr[4];
    #pragma unroll
    for (int mi = 0; mi < 2; mi++) af[mi] = frag_sw(&As[1][0], wr * 32 + mi * 16 + fr, q8);
    #pragma unroll
    for (int ni = 0; ni < 4; ni++) bfr[ni] = frag_sw(&Bs[1][0], wc * 64 + ni * 16 + fr, q8);
    #pragma unroll
    for (int mi = 0; mi < 2; mi++)
      #pragma unroll
      for (int ni = 0; ni < 4; ni++)
        acc[mi][ni] = __builtin_amdgcn_mfma_f32_16x16x32_bf16(af[mi], bfr[ni], acc[mi][ni], 0, 0, 0);
  }

  const int colb = n0 + wc * 64 + fr;
  const int rowb = m0 + wr * 32 + (ln >> 4) * 4;
  #pragma unroll
  for (int mi = 0; mi < 2; mi++)
    #pragma unroll
    for (int r = 0; r < 4; r++) {
      const int mr = rowb + mi * 16 + r;
      #pragma unroll
      for (int ni = 0; ni < 4; ni++)
        Cg[((long)bz << 20) + (long)mr * 512 + colb + ni * 16] = f2bf(acc[mi][ni][r]);
    }
}

// ---------------- fused theta/phi conv + G: one staging of x ---------------
// Blocks 0..255 (x): theta = imgT·wth^T + bth  AND  G = wg·img + bg.
// Blocks 256..511 (y): phi only. Per step: img reg-staged by waves 0-3,
// weights async by waves 4-7 (wth/wph -> Bs; wg -> Cs for x-blocks).
// G uses the SAME img tile with swapped MFMA operand order.
__global__ __launch_bounds__(512, 2)
void conv_ptg(const float* __restrict__ x, const float* __restrict__ y,
              const short* __restrict__ wth, const short* __restrict__ wph,
              const short* __restrict__ wg,
              const float* __restrict__ bth, const float* __restrict__ bph,
              const float* __restrict__ bg,
              short* __restrict__ TPT2, short* __restrict__ G)
{
  __shared__ __align__(16) short As[2][128 * 32];   // img [px][32c], swizzled
  __shared__ __align__(16) short Bs[2][256 * 32];   // wth/wph, swizzled
  __shared__ __align__(16) short Cs[2][256 * 32];   // wg, swizzled (x-blocks)
  const int slab = blockIdx.x;                      // 0..511
  const bool isphi = slab >= 256;
  const bool doG = !isphi;
  const int s2 = slab & 255;
  const int img = s2 >> 5;
  const float* src = (isphi ? y : x) + (long)img * (512L * 4096);
  const int px0 = (s2 & 31) * 128;
  const long m0 = (long)slab * 128;
  const short* W = isphi ? wph : wth;
  const float* bias = isphi ? bph : bth;
  const int t = threadIdx.x;
  const int wv = t >> 6, ln = t & 63;
  const int wpx = wv >> 2, wic = wv & 3;            // theta: [wpx*64 px][wic*64 ic]
  const int fr = ln & 15, q8 = (ln >> 4) * 8;
  const int g4 = (t >> 5) * 4, p4 = (t & 31) * 4;   // img stager coords
  const int w2 = wv - 4;                            // weight stager wave
  const int kcs = ((ln & 3) ^ (ln >> 4)) * 8;       // weight source swizzle

  f32x4 acc[4][4], accg[4][4];
  #pragma unroll
  for (int i = 0; i < 4; i++)
    #pragma unroll
    for (int j = 0; j < 4; j++)
      #pragma unroll
      for (int r = 0; r < 4; r++) { acc[i][j][r] = 0.f; accg[i][j][r] = 0.f; }

  // ---- prologue: fill buffer 0 (k-step 0)
  if (t >= 256) {
    #pragma unroll
    for (int j = 0; j < 4; j++)
      async_ld16(W + (long)(w2 * 64 + j * 16 + (ln >> 2)) * 512 + kcs,
                 &Bs[0][(w2 * 64 + j * 16) * 32]);
    if (doG) {
      #pragma unroll
      for (int j = 0; j < 4; j++)
        async_ld16(wg + (long)(w2 * 64 + j * 16 + (ln >> 2)) * 512 + kcs,
                   &Cs[0][(w2 * 64 + j * 16) * 32]);
    }
  } else {
    f32x4 r[4];
    #pragma unroll
    for (int i = 0; i < 4; i++)
      r[i] = *(const f32x4*)&src[(long)(g4 + i) * 4096 + px0 + p4];
    #pragma unroll
    for (int j = 0; j < 4; j++) {
      short4v w;
      w[0] = f2bf(r[0][j]); w[1] = f2bf(r[1][j]); w[2] = f2bf(r[2][j]); w[3] = f2bf(r[3][j]);
      const int px = p4 + j;
      const int u = (g4 >> 3) ^ ((px >> 2) & 3);
      *(short4v*)&As[0][px * 32 + u * 8 + (g4 & 4)] = w;
    }
  }
  __syncthreads();

  // ---- main loop: compute k-1 while staging k
  for (int k = 1; k < 16; k++) {
    const int cur = (k - 1) & 1, nxt = k & 1;
    f32x4 r[4];
    if (t >= 256) {
      #pragma unroll
      for (int j = 0; j < 4; j++)
        async_ld16(W + (long)(w2 * 64 + j * 16 + (ln >> 2)) * 512 + k * 32 + kcs,
                   &Bs[nxt][(w2 * 64 + j * 16) * 32]);
      if (doG) {
        #pragma unroll
        for (int j = 0; j < 4; j++)
          async_ld16(wg + (long)(w2 * 64 + j * 16 + (ln >> 2)) * 512 + k * 32 + kcs,
                     &Cs[nxt][(w2 * 64 + j * 16) * 32]);
      }
    } else {
      #pragma unroll
      for (int i = 0; i < 4; i++)
        r[i] = *(const f32x4*)&src[(long)(k * 32 + g4 + i) * 4096 + px0 + p4];
    }
    short8 af[4], bfv[4];
    #pragma unroll
    for (int mi = 0; mi < 4; mi++) af[mi] = frag_sw(&As[cur][0], wpx * 64 + mi * 16 + fr, q8);
    #pragma unroll
    for (int ni = 0; ni < 4; ni++) bfv[ni] = frag_sw(&Bs[cur][0], wic * 64 + ni * 16 + fr, q8);
    #pragma unroll
    for (int mi = 0; mi < 4; mi++)
      #pragma unroll
      for (int ni = 0; ni < 4; ni++)
        acc[mi][ni] = __builtin_amdgcn_mfma_f32_16x16x32_bf16(af[mi], bfv[ni], acc[mi][ni], 0, 0, 0);
    if (doG) {
      short8 ag[4], bg2[4];
      #pragma unroll
      for (int mi = 0; mi < 4; mi++) ag[mi] = frag_sw(&Cs[cur][0], wic * 64 + mi * 16 + fr, q8);
      #pragma unroll
      for (int ni = 0; ni < 4; ni++) bg2[ni] = frag_sw(&As[cur][0], wpx * 64 + ni * 16 + fr, q8);
      #pragma unroll
      for (int mi = 0; mi < 4; mi++)
        #pragma unroll
        for (int ni = 0; ni < 4; ni++)
          accg[mi][ni] = __builtin_amdgcn_mfma_f32_16x16x32_bf16(ag[mi], bg2[ni], accg[mi][ni], 0, 0, 0);
    }
    if (t < 256) {
      #pragma unroll
      for (int j = 0; j < 4; j++) {
        short4v w;
        w[0] = f2bf(r[0][j]); w[1] = f2bf(r[1][j]); w[2] = f2bf(r[2][j]); w[3] = f2bf(r[3][j]);
        const int px = p4 + j;
        const int u = (g4 >> 3) ^ ((px >> 2) & 3);
        *(short4v*)&As[nxt][px * 32 + u * 8 + (g4 & 4)] = w;
      }
    }
    __syncthreads();
  }

  // ---- final k-step (buffer 1)
  {
    short8 af[4], bfv[4];
    #pragma unroll
    for (int mi = 0; mi < 4; mi++) af[mi] = frag_sw(&As[1][0], wpx * 64 + mi * 16 + fr, q8);
    #pragma unroll
    for (int ni = 0; ni < 4; ni++) bfv[ni] = frag_sw(&Bs[1][0], wic * 64 + ni * 16 + fr, q8);
    #pragma unroll
    for (int mi = 0; mi < 4; mi++)
      #pragma unroll
      for (int ni = 0; ni < 4; ni++)
        acc[mi][ni] = __builtin_amdgcn_mfma_f32_16x16x32_bf16(af[mi], bfv[ni], acc[mi][ni], 0, 0, 0);
    if (doG) {
      short8 ag[4], bg2[4];
      #pragma unroll
      for (int mi = 0; mi < 4; mi++) ag[mi] = frag_sw(&Cs[1][0], wic * 64 + mi * 16 + fr, q8);
      #pragma unroll
      for (int ni = 0; ni < 4; ni++) bg2[ni] = frag_sw(&As[1][0], wpx * 64 + ni * 16 + fr, q8);
      #pragma unroll
      for (int mi = 0; mi < 4; mi++)
        #pragma unroll
        for (int ni = 0; ni < 4; ni++)
          accg[mi][ni] = __builtin_amdgcn_mfma_f32_16x16x32_bf16(ag[mi], bg2[ni], accg[mi][ni], 0, 0, 0);
    }
  }

  // ---- theta/phi epilogue
  const int colic = wic * 64 + fr;
  float cb[4];
  #pragma unroll
  for (int ni = 0; ni < 4; ni++) cb[ni] = bias[colic + ni * 16];
  #pragma unroll
  for (int mi = 0; mi < 4; mi++)
    #pragma unroll
    for (int r = 0; r < 4; r++) {
      const long m = m0 + wpx * 64 + mi * 16 + (ln >> 4) * 4 + r;
      #pragma unroll
      for (int ni = 0; ni < 4; ni++)
        TPT2[m * 256 + colic + ni * 16] = f2bf(acc[mi][ni][r] + cb[ni]);
    }

  // ---- G epilogue (x-blocks): G[ic][px] per image
  if (doG) {
    const int colpx = px0 + wpx * 64 + fr;
    #pragma unroll
    for (int mi = 0; mi < 4; mi++)
      #pragma unroll
      for (int r = 0; r < 4; r++) {
        const int ic = wic * 64 + mi * 16 + (ln >> 4) * 4 + r;
        const float badd = bg[ic];
        #pragma unroll
        for (int ni = 0; ni < 4; ni++)
          G[((long)img << 20) + (long)ic * 4096 + colpx + ni * 16] = f2bf(accg[mi][ni][r] + badd);
      }
  }
}

// ---------------- scores v2: dbuf, single barrier, swizzled ----------------
__global__ __launch_bounds__(256)
void scores_k(const short* __restrict__ TT2, const short* __restrict__ PT2,
              short* __restrict__ ST, float* __restrict__ pstats)
{
  __shared__ __align__(16) short As[2][128 * 32];
  __shared__ __align__(16) short Bs[2][128 * 32];
  const int bz = blockIdx.z, by = blockIdx.y, bx = blockIdx.x;
  const int t = threadIdx.x;
  const int wv = t >> 6, ln = t & 63;
  const int wm = (wv >> 1) * 64, wn = (wv & 1) * 64;
  const int fr = ln & 15, q8 = (ln >> 4) * 8;
  const int rowA = t >> 2;
  const int kcs = ((t & 3) ^ ((t >> 4) & 3)) * 8;

  const short* Abase = TT2 + ((long)(bz * 4096 + by * 128)) * 256;
  const short* Bbase = PT2 + ((long)(bz * 4096 + bx * 128)) * 256;

  f32x4 acc[4][4];
  #pragma unroll
  for (int i = 0; i < 4; i++)
    #pragma unroll
    for (int j = 0; j < 4; j++)
      #pragma unroll
      for (int r = 0; r < 4; r++) acc[i][j][r] = 0.f;

  #define SC_STAGE(s, buf)                                                     \
    {                                                                          \
      const long hoff = (long)((s) >> 3) * 2048 * 256;                         \
      const int kk = ((s) & 7) * 32;                                           \
      _Pragma("unroll")                                                        \
      for (int sv = 0; sv < 2; sv++) {                                         \
        async_ld16(Abase + hoff + (long)(sv * 64 + rowA) * 256 + kk + kcs,     \
                   &As[buf][0] + (sv * 256 + wv * 64) * 8);                    \
        async_ld16(Bbase + hoff + (long)(sv * 64 + rowA) * 256 + kk + kcs,     \
                   &Bs[buf][0] + (sv * 256 + wv * 64) * 8);                    \
      }                                                                        \
    }

  SC_STAGE(0, 0);
  __syncthreads();
  for (int s = 1; s < 16; s++) {
    const int cur = (s - 1) & 1, nxt = s & 1;
    SC_STAGE(s, nxt);
    short8 af[4], bfr[4];
    #pragma unroll
    for (int mi = 0; mi < 4; mi++) af[mi] = frag_sw(&As[cur][0], wm + mi * 16 + fr, q8);
    #pragma unroll
    for (int ni = 0; ni < 4; ni++) bfr[ni] = frag_sw(&Bs[cur][0], wn + ni * 16 + fr, q8);
    #pragma unroll
    for (int mi = 0; mi < 4; mi++)
      #pragma unroll
      for (int ni = 0; ni < 4; ni++)
        acc[mi][ni] = __builtin_amdgcn_mfma_f32_16x16x32_bf16(af[mi], bfr[ni], acc[mi][ni], 0, 0, 0);
    __syncthreads();
  }
  {
    short8 af[4], bfr[4];
    #pragma unroll
    for (int mi = 0; mi < 4; mi++) af[mi] = frag_sw(&As[1][0], wm + mi * 16 + fr, q8);
    #pragma unroll
    for (int ni = 0; ni < 4; ni++) bfr[ni] = frag_sw(&Bs[1][0], wn + ni * 16 + fr, q8);
    #pragma unroll
    for (int mi = 0; mi < 4; mi++)
      #pragma unroll
      for (int ni = 0; ni < 4; ni++)
        acc[mi][ni] = __builtin_amdgcn_mfma_f32_16x16x32_bf16(af[mi], bfr[ni], acc[mi][ni], 0, 0, 0);
  }
  #undef SC_STAGE

  const int colb = bx * 128 + wn + fr;
  const int rowb = by * 128 + wm + (ln >> 4) * 4;
  short* base = ST + ((long)bz << 22);
  float ps[4] = {0.f, 0.f, 0.f, 0.f};
  #pragma unroll
  for (int mi = 0; mi < 4; mi++)
    #pragma unroll
    for (int r = 0; r < 4; r++) {
      const long mr = rowb + mi * 16 + r;
      #pragma unroll
      for (int ni = 0; ni < 4; ni++) {
        float e = __expf(acc[mi][ni][r]);
        base[mr * 2048 + colb + ni * 16] = f2bf(e);
        ps[ni] += e;
      }
    }
  #pragma unroll
  for (int ni = 0; ni < 4; ni++) {
    ps[ni] += __shfl_xor(ps[ni], 16);
    ps[ni] += __shfl_xor(ps[ni], 32);
  }
  float* part = (float*)&As[0][0];
  if (ln < 16) {
    #pragma unroll
    for (int ni = 0; ni < 4; ni++)
      part[(wv >> 1) * 128 + wn + ni * 16 + fr] = ps[ni];
  }
  __syncthreads();
  if (t < 128)
    pstats[((long)(bz * 16 + by)) * 2048 + bx * 128 + t] = part[t] + part[128 + t];
}

// ---------------- reduce 16 partials -> invZ per column --------------------
__global__ __launch_bounds__(256)
void zfinal(const float* __restrict__ pstats, float* __restrict__ invZ)
{
  const int g = blockIdx.x * 256 + threadIdx.x;
  const int b = g >> 11, col = g & 2047;
  float S = 0.f;
  #pragma unroll
  for (int rc = 0; rc < 16; rc++) S += pstats[((long)(b * 16 + rc)) * 2048 + col];
  invZ[g] = 1.f / S;
}

// ---------------- G *= invZ[m] (in place) ----------------------------------
__global__ __launch_bounds__(256)
void g_scale(short* __restrict__ G, const float* __restrict__ invZ)
{
  const long base = ((long)blockIdx.x * 256 + threadIdx.x) * 8;
  const int bz = (int)(base >> 20);
  const int n2 = (int)(base & 4095);
  const float* z = invZ + bz * 2048 + (n2 & 2047);
  short8 v = *(short8*)&G[base];
  f32x4 z0 = *(const f32x4*)z;
  f32x4 z1 = *(const f32x4*)(z + 4);
  #pragma unroll
  for (int j = 0; j < 4; j++) { v[j] = f2bf(bf2f(v[j]) * z0[j]); v[4 + j] = f2bf(bf2f(v[4 + j]) * z1[j]); }
  *(short8*)&G[base] = v;
}

// ---------------- mask GEMM v2: dbuf, single barrier, swizzled -------------
__global__ __launch_bounds__(256)
void mask_k(const short* __restrict__ Wm20, const short* __restrict__ Wm21,
            const short* __restrict__ OVT, const float* __restrict__ bmask,
            const float* __restrict__ x, float* __restrict__ out)
{
  __shared__ __align__(16) short As[2][128 * 32];
  __shared__ __align__(16) short Bs[2][128 * 32];
  const int bz = blockIdx.z;
  const int n0 = blockIdx.x * 128;
  const int m0 = blockIdx.y * 128;
  const short* A = (n0 >= 2048) ? Wm21 : Wm20;
  const short* B = OVT + ((long)bz << 20) + (long)(n0 & 2047) * 512;
  const int t = threadIdx.x;
  const int wv = t >> 6, ln = t & 63;
  const int wm = (wv >> 1) * 64, wn = (wv & 1) * 64;
  const int fr = ln & 15, q8 = (ln >> 4) * 8;
  const int rowA = t >> 2;
  const int kcs = ((t & 3) ^ ((t >> 4) & 3)) * 8;

  f32x4 acc[4][4];
  #pragma unroll
  for (int i = 0; i < 4; i++)
    #pragma unroll
    for (int j = 0; j < 4; j++)
      #pragma unroll
      for (int r = 0; r < 4; r++) acc[i][j][r] = 0.f;

  #define MK_STAGE(s, buf)                                                     \
    {                                                                          \
      const int kk = (s) * 32;                                                 \
      _Pragma("unroll")                                                        \
      for (int sv = 0; sv < 2; sv++) {                                         \
        async_ld16(A + (long)(m0 + sv * 64 + rowA) * 512 + kk + kcs,           \
                   &As[buf][0] + (sv * 256 + wv * 64) * 8);                    \
        async_ld16(B + (long)(sv * 64 + rowA) * 512 + kk + kcs,                \
                   &Bs[buf][0] + (sv * 256 + wv * 64) * 8);                    \
      }                                                                        \
    }

  MK_STAGE(0, 0);
  __syncthreads();
  for (int s = 1; s < 16; s++) {
    const int cur = (s - 1) & 1, nxt = s & 1;
    MK_STAGE(s, nxt);
    short8 af[4], bfr[4];
    #pragma unroll
    for (int mi = 0; mi < 4; mi++) af[mi] = frag_sw(&As[cur][0], wm + mi * 16 + fr, q8);
    #pragma unroll
    for (int ni = 0; ni < 4; ni++) bfr[ni] = frag_sw(&Bs[cur][0], wn + ni * 16 + fr, q8);
    #pragma unroll
    for (int mi = 0; mi < 4; mi++)
      #pragma unroll
      for (int ni = 0; ni < 4; ni++)
        acc[mi][ni] = __builtin_amdgcn_mfma_f32_16x16x32_bf16(af[mi], bfr[ni], acc[mi][ni], 0, 0, 0);
    __syncthreads();
  }
  {
    short8 af[4], bfr[4];
    #pragma unroll
    for (int mi = 0; mi < 4; mi++) af[mi] = frag_sw(&As[1][0], wm + mi * 16 + fr, q8);
    #pragma unroll
    for (int ni = 0; ni < 4; ni++) bfr[ni] = frag_sw(&Bs[1][0], wn + ni * 16 + fr, q8);
    #pragma unroll
    for (int mi = 0; mi < 4; mi++)
      #pragma unroll
      for (int ni = 0; ni < 4; ni++)
        acc[mi][ni] = __builtin_amdgcn_mfma_f32_16x16x32_bf16(af[mi], bfr[ni], acc[mi][ni], 0, 0, 0);
  }
  #undef MK_STAGE

  const int colb = n0 + wn + fr;
  const int rowb = m0 + wm + (ln >> 4) * 4;
  #pragma unroll
  for (int mi = 0; mi < 4; mi++)
    #pragma unroll
    for (int r = 0; r < 4; r++) {
      const int mr = rowb + mi * 16 + r;
      const float badd = bmask[mr];
      const long rbase = ((long)bz * 512 + mr) * 4096;
      #pragma unroll
      for (int ni = 0; ni < 4; ni++) {
        const int cc = colb + ni * 16;
        out[rbase + cc] = acc[mi][ni][r] + badd + x[rbase + cc];
      }
    }
}

// ---------------- weight prep ----------------------------------------------
__global__ __launch_bounds__(256)
void wconv2(const float* w_phi, const float* w_theta, const float* w_g,
            const float* w_mask,
            short* wph, short* wth, short* wg, short* Wm20, short* Wm21)
{
  const int seg = blockIdx.x >> 6;
  const int blk = blockIdx.x & 63;
  const int i0 = blk * 2048 + threadIdx.x * 8;
  if (seg < 3) {
    const float* s = seg == 0 ? w_phi : seg == 1 ? w_theta : w_g;
    short* d = seg == 0 ? wph : seg == 1 ? wth : wg;
    f32x4 a = *(const f32x4*)&s[i0];
    f32x4 b = *(const f32x4*)&s[i0 + 4];
    short8 o;
    #pragma unroll
    for (int j = 0; j < 4; j++) { o[j] = f2bf(a[j]); o[4 + j] = f2bf(b[j]); }
    *(short8*)&d[i0] = o;
  } else {
    const int o = i0 >> 8;
    f32x4 a = *(const f32x4*)&w_mask[i0];
    f32x4 b = *(const f32x4*)&w_mask[i0 + 4];
    short v[8];
    #pragma unroll
    for (int j = 0; j < 4; j++) { v[j] = f2bf(a[j]); v[4 + j] = f2bf(b[j]); }
    short8 a0, a1, b0, b1;
    #pragma unroll
    for (int j = 0; j < 4; j++) {
      a0[2 * j] = v[j];     a0[2 * j + 1] = 0;
      a1[2 * j] = v[4 + j]; a1[2 * j + 1] = 0;
      b0[2 * j] = 0;        b0[2 * j + 1] = v[j];
      b1[2 * j] = 0;        b1[2 * j + 1] = v[4 + j];
    }
    const long base = (long)o * 512 + 2 * (i0 & 255);
    *(short8*)&Wm20[base] = a0; *(short8*)&Wm20[base + 8] = a1;
    *(short8*)&Wm21[base] = b0; *(short8*)&Wm21[base + 8] = b1;
  }
}

// ---------------------------------------------------------------------------
extern "C" void kernel_launch(void* const* d_in, const int* in_sizes, int n_in,
                              void* d_out, int out_size, void* d_ws, size_t ws_size,
                              hipStream_t stream)
{
  (void)in_sizes; (void)n_in; (void)out_size; (void)ws_size;
  const float* x       = (const float*)d_in[0];
  const float* y       = (const float*)d_in[1];
  const float* w_phi   = (const float*)d_in[2];
  const float* b_phi   = (const float*)d_in[3];
  const float* w_theta = (const float*)d_in[4];
  const float* b_theta = (const float*)d_in[5];
  const float* w_g     = (const float*)d_in[6];
  const float* b_g     = (const float*)d_in[7];
  const float* w_mask  = (const float*)d_in[8];
  const float* b_mask  = (const float*)d_in[9];
  float* out = (float*)d_out;

  char* ws = (char*)d_ws;
  const long MB = 1L << 20;
  short* wph  = (short*)(ws + 0);
  short* wth  = (short*)(ws + 256 * 1024);
  short* wg   = (short*)(ws + 512 * 1024);
  short* Wm20 = (short*)(ws + 768 * 1024);
  short* Wm21 = (short*)(ws + 1280 * 1024);
  short* TPT2 = (short*)(ws + 66 * MB);   // [65536][256], 32MB
  short* G    = (short*)(ws + 98 * MB);   // [8][256][4096], 16MB
  short* ST   = (short*)(ws + 2 * MB);    // [8][2048][2048] E, 64MB
  float* pstats = (float*)(ws + 114 * MB);
  float* invZ   = (float*)(ws + 115 * MB);
  short* OVT  = (short*)(ws + 66 * MB);   // [8][2048][512], 16MB (over TPT2)

  dim3 blk(256, 1, 1);
  dim3 blk8(512, 1, 1);

  wconv2<<<dim3(256, 1, 1), blk, 0, stream>>>(w_phi, w_theta, w_g, w_mask,
                                              wph, wth, wg, Wm20, Wm21);

  conv_ptg<<<dim3(512, 1, 1), blk8, 0, stream>>>(x, y, wth, wph, wg,
                                                 b_theta, b_phi, b_g, TPT2, G);

  scores_k<<<dim3(16, 16, 8), blk, 0, stream>>>(TPT2, TPT2 + 32768L * 256, ST, pstats);
  zfinal<<<dim3(64, 1, 1), blk, 0, stream>>>(pstats, invZ);
  g_scale<<<dim3(4096, 1, 1), blk, 0, stream>>>(G, invZ);

  ov_k<<<dim3(512, 1, 1), blk8, 0, stream>>>(ST, G, OVT);

  mask_k<<<dim3(32, 4, 8), blk, 0, stream>>>(Wm20, Wm21, OVT, b_mask, x, out);
}

// Round 9
// 357.360 us; speedup vs baseline: 1.0418x; 1.0418x over previous
//
#include <hip/hip_runtime.h>
#include <hip/hip_bf16.h>

// Non-local block, B=8 C=512 H=W=64, IC=256, N2=HW=4096, N=2048 (folded).
//
// Round-12: ov_k/scores_k/mask_k converted to TRIPLE-buffered counted-vmcnt
// pipelines (T4): stage tile k+2 while computing tile k; end-of-iteration
// barrier = raw s_barrier + s_waitcnt vmcnt(L) lgkmcnt(0) where L = loads
// issued per iteration (exempts the newest batch, drains the 2-iterations-old
// batch that the NEXT iteration consumes). Loads get 2x MFMA-time in flight;
// vmcnt(0) only at the tail. Depth-2 dbuf provably cannot do this (the buffer
// staged at iter k is consumed right after iter k's barrier -> full drain).
// conv_ptg (fused theta/phi/G) unchanged from round 11.

typedef __attribute__((ext_vector_type(8))) short short8;
typedef __attribute__((ext_vector_type(4))) short short4v;
typedef __attribute__((ext_vector_type(4))) float f32x4;

__device__ __forceinline__ short f2bf(float f) {
  union { __hip_bfloat16 h; short s; } u; u.h = __float2bfloat16(f); return u.s;
}
__device__ __forceinline__ float bf2f(short s) {
  union { short s; __hip_bfloat16 h; } u; u.s = s; return __bfloat162float(u.h);
}

__device__ __forceinline__ void async_ld16(const void* g, void* l) {
  __builtin_amdgcn_global_load_lds(
      (const __attribute__((address_space(1))) unsigned int*)(unsigned long long)g,
      (__attribute__((address_space(3))) unsigned int*)(unsigned int)(unsigned long long)l,
      16, 0, 0);
}

// counted barrier: drain all but the newest N outstanding vmem ops, all LDS ops
#define CBAR(N)                                                                \
  asm volatile("s_waitcnt vmcnt(" #N ") lgkmcnt(0)" ::: "memory");             \
  __builtin_amdgcn_s_barrier();

// swizzled b128 fragment read from a [row][32-short] tile whose 16B-unit u
// holds global chunk u ^ ((row>>2)&3)
__device__ __forceinline__ short8 frag_sw(const short* Ds, int row, int q8)
{
  return *(const short8*)&Ds[row * 32 + (((q8 >> 3) ^ ((row >> 2) & 3)) << 3)];
}

// ---------------- OV GEMM v3: 3-deep counted pipeline ----------------------
// OVT[b][n][c] = sum_m E[n][m]*G''[c][m]. 512 blocks; XCD-local slab map.
__global__ __launch_bounds__(512, 4)
void ov_k(const short* __restrict__ Eg, const short* __restrict__ Gg,
          short* __restrict__ Cg)
{
  const int L = blockIdx.x;
  const int xcd = L & 7, k = L >> 3;
  const int slab = xcd + ((k >> 2) << 3);   // 0..127
  const int bz = slab >> 4, by = slab & 15, bx = k & 3;

  __shared__ __align__(16) short As[3][128 * 32];
  __shared__ __align__(16) short Bs[3][128 * 32];
  const short* A = Eg + ((long)bz << 22);
  const short* B = Gg + ((long)bz << 20);
  const int m0 = by * 128;
  const int n0 = bx * 128;
  const int t = threadIdx.x;
  const int wv = t >> 6, ln = t & 63;
  const int wr = wv >> 1, wc = wv & 1;
  const int fr = ln & 15, q8 = (ln >> 4) * 8;
  const int rowA = t >> 2;
  const int kcs = ((t & 3) ^ ((t >> 4) & 3)) * 8;   // inverse-swizzled source chunk

  f32x4 acc[2][4];
  #pragma unroll
  for (int i = 0; i < 2; i++)
    #pragma unroll
    for (int j = 0; j < 4; j++)
      #pragma unroll
      for (int r = 0; r < 4; r++) acc[i][j][r] = 0.f;

  #define OV_STAGE(kt, buf)                                                    \
    async_ld16(A + (long)(m0 + rowA) * 2048 + (kt) * 32 + kcs,                 \
               &As[buf][0] + wv * 512);                                        \
    async_ld16(B + (long)(n0 + rowA) * 2048 + (kt) * 32 + kcs,                 \
               &Bs[buf][0] + wv * 512);

  #define OV_COMPUTE(cbuf)                                                     \
    {                                                                          \
      const short* Ac = &As[cbuf][0];                                          \
      const short* Bc = &Bs[cbuf][0];                                          \
      short8 af[2], bfr[4];                                                    \
      _Pragma("unroll")                                                        \
      for (int mi = 0; mi < 2; mi++)                                           \
        af[mi] = frag_sw(Ac, wr * 32 + mi * 16 + fr, q8);                      \
      _Pragma("unroll")                                                        \
      for (int ni = 0; ni < 4; ni++)                                           \
        bfr[ni] = frag_sw(Bc, wc * 64 + ni * 16 + fr, q8);                     \
      _Pragma("unroll")                                                        \
      for (int mi = 0; mi < 2; mi++)                                           \
        _Pragma("unroll")                                                      \
        for (int ni = 0; ni < 4; ni++)                                         \
          acc[mi][ni] = __builtin_amdgcn_mfma_f32_16x16x32_bf16(               \
              af[mi], bfr[ni], acc[mi][ni], 0, 0, 0);                          \
    }

  OV_STAGE(0, 0);
  OV_STAGE(1, 1);
  CBAR(2)                       // drain tile-0 batch; tile-1 stays in flight

  int cs = 0, ss = 2;
  for (int kt = 0; kt < 62; kt++) {
    OV_STAGE(kt + 2, ss);
    OV_COMPUTE(cs);
    CBAR(2)                     // drain tile-(kt+1) batch; tile-(kt+2) flies
    cs = (cs == 2) ? 0 : cs + 1;
    ss = (ss == 2) ? 0 : ss + 1;
  }
  OV_COMPUTE(2)                 // tile 62 (62%3==2)
  CBAR(0)                       // drain tile-63 batch
  OV_COMPUTE(0)                 // tile 63 (63%3==0)
  #undef OV_STAGE
  #undef OV_COMPUTE

  const int colb = n0 + wc * 64 + fr;
  const int rowb = m0 + wr * 32 + (ln >> 4) * 4;
  #pragma unroll
  for (int mi = 0; mi < 2; mi++)
    #pragma unroll
    for (int r = 0; r < 4; r++) {
      const int mr = rowb + mi * 16 + r;
      #pragma unroll
      for (int ni = 0; ni < 4; ni++)
        Cg[((long)bz << 20) + (long)mr * 512 + colb + ni * 16] = f2bf(acc[mi][ni][r]);
    }
}

// ---------------- fused theta/phi conv + G: one staging of x ---------------
// Blocks 0..255 (x): theta = imgT·wth^T + bth  AND  G = wg·img + bg.
// Blocks 256..511 (y): phi only. Per step: img reg-staged by waves 0-3,
// weights async by waves 4-7 (wth/wph -> Bs; wg -> Cs for x-blocks).
// G uses the SAME img tile with swapped MFMA operand order.
__global__ __launch_bounds__(512, 2)
void conv_ptg(const float* __restrict__ x, const float* __restrict__ y,
              const short* __restrict__ wth, const short* __restrict__ wph,
              const short* __restrict__ wg,
              const float* __restrict__ bth, const float* __restrict__ bph,
              const float* __restrict__ bg,
              short* __restrict__ TPT2, short* __restrict__ G)
{
  __shared__ __align__(16) short As[2][128 * 32];   // img [px][32c], swizzled
  __shared__ __align__(16) short Bs[2][256 * 32];   // wth/wph, swizzled
  __shared__ __align__(16) short Cs[2][256 * 32];   // wg, swizzled (x-blocks)
  const int slab = blockIdx.x;                      // 0..511
  const bool isphi = slab >= 256;
  const bool doG = !isphi;
  const int s2 = slab & 255;
  const int img = s2 >> 5;
  const float* src = (isphi ? y : x) + (long)img * (512L * 4096);
  const int px0 = (s2 & 31) * 128;
  const long m0 = (long)slab * 128;
  const short* W = isphi ? wph : wth;
  const float* bias = isphi ? bph : bth;
  const int t = threadIdx.x;
  const int wv = t >> 6, ln = t & 63;
  const int wpx = wv >> 2, wic = wv & 3;            // theta: [wpx*64 px][wic*64 ic]
  const int fr = ln & 15, q8 = (ln >> 4) * 8;
  const int g4 = (t >> 5) * 4, p4 = (t & 31) * 4;   // img stager coords
  const int w2 = wv - 4;                            // weight stager wave
  const int kcs = ((ln & 3) ^ (ln >> 4)) * 8;       // weight source swizzle

  f32x4 acc[4][4], accg[4][4];
  #pragma unroll
  for (int i = 0; i < 4; i++)
    #pragma unroll
    for (int j = 0; j < 4; j++)
      #pragma unroll
      for (int r = 0; r < 4; r++) { acc[i][j][r] = 0.f; accg[i][j][r] = 0.f; }

  // ---- prologue: fill buffer 0 (k-step 0)
  if (t >= 256) {
    #pragma unroll
    for (int j = 0; j < 4; j++)
      async_ld16(W + (long)(w2 * 64 + j * 16 + (ln >> 2)) * 512 + kcs,
                 &Bs[0][(w2 * 64 + j * 16) * 32]);
    if (doG) {
      #pragma unroll
      for (int j = 0; j < 4; j++)
        async_ld16(wg + (long)(w2 * 64 + j * 16 + (ln >> 2)) * 512 + kcs,
                   &Cs[0][(w2 * 64 + j * 16) * 32]);
    }
  } else {
    f32x4 r[4];
    #pragma unroll
    for (int i = 0; i < 4; i++)
      r[i] = *(const f32x4*)&src[(long)(g4 + i) * 4096 + px0 + p4];
    #pragma unroll
    for (int j = 0; j < 4; j++) {
      short4v w;
      w[0] = f2bf(r[0][j]); w[1] = f2bf(r[1][j]); w[2] = f2bf(r[2][j]); w[3] = f2bf(r[3][j]);
      const int px = p4 + j;
      const int u = (g4 >> 3) ^ ((px >> 2) & 3);
      *(short4v*)&As[0][px * 32 + u * 8 + (g4 & 4)] = w;
    }
  }
  __syncthreads();

  // ---- main loop: compute k-1 while staging k
  for (int k = 1; k < 16; k++) {
    const int cur = (k - 1) & 1, nxt = k & 1;
    f32x4 r[4];
    if (t >= 256) {
      #pragma unroll
      for (int j = 0; j < 4; j++)
        async_ld16(W + (long)(w2 * 64 + j * 16 + (ln >> 2)) * 512 + k * 32 + kcs,
                   &Bs[nxt][(w2 * 64 + j * 16) * 32]);
      if (doG) {
        #pragma unroll
        for (int j = 0; j < 4; j++)
          async_ld16(wg + (long)(w2 * 64 + j * 16 + (ln >> 2)) * 512 + k * 32 + kcs,
                     &Cs[nxt][(w2 * 64 + j * 16) * 32]);
      }
    } else {
      #pragma unroll
      for (int i = 0; i < 4; i++)
        r[i] = *(const f32x4*)&src[(long)(k * 32 + g4 + i) * 4096 + px0 + p4];
    }
    short8 af[4], bfv[4];
    #pragma unroll
    for (int mi = 0; mi < 4; mi++) af[mi] = frag_sw(&As[cur][0], wpx * 64 + mi * 16 + fr, q8);
    #pragma unroll
    for (int ni = 0; ni < 4; ni++) bfv[ni] = frag_sw(&Bs[cur][0], wic * 64 + ni * 16 + fr, q8);
    #pragma unroll
    for (int mi = 0; mi < 4; mi++)
      #pragma unroll
      for (int ni = 0; ni < 4; ni++)
        acc[mi][ni] = __builtin_amdgcn_mfma_f32_16x16x32_bf16(af[mi], bfv[ni], acc[mi][ni], 0, 0, 0);
    if (doG) {
      short8 ag[4], bg2[4];
      #pragma unroll
      for (int mi = 0; mi < 4; mi++) ag[mi] = frag_sw(&Cs[cur][0], wic * 64 + mi * 16 + fr, q8);
      #pragma unroll
      for (int ni = 0; ni < 4; ni++) bg2[ni] = frag_sw(&As[cur][0], wpx * 64 + ni * 16 + fr, q8);
      #pragma unroll
      for (int mi = 0; mi < 4; mi++)
        #pragma unroll
        for (int ni = 0; ni < 4; ni++)
          accg[mi][ni] = __builtin_amdgcn_mfma_f32_16x16x32_bf16(ag[mi], bg2[ni], accg[mi][ni], 0, 0, 0);
    }
    if (t < 256) {
      #pragma unroll
      for (int j = 0; j < 4; j++) {
        short4v w;
        w[0] = f2bf(r[0][j]); w[1] = f2bf(r[1][j]); w[2] = f2bf(r[2][j]); w[3] = f2bf(r[3][j]);
        const int px = p4 + j;
        const int u = (g4 >> 3) ^ ((px >> 2) & 3);
        *(short4v*)&As[nxt][px * 32 + u * 8 + (g4 & 4)] = w;
      }
    }
    __syncthreads();
  }

  // ---- final k-step (buffer 1)
  {
    short8 af[4], bfv[4];
    #pragma unroll
    for (int mi = 0; mi < 4; mi++) af[mi] = frag_sw(&As[1][0], wpx * 64 + mi * 16 + fr, q8);
    #pragma unroll
    for (int ni = 0; ni < 4; ni++) bfv[ni] = frag_sw(&Bs[1][0], wic * 64 + ni * 16 + fr, q8);
    #pragma unroll
    for (int mi = 0; mi < 4; mi++)
      #pragma unroll
      for (int ni = 0; ni < 4; ni++)
        acc[mi][ni] = __builtin_amdgcn_mfma_f32_16x16x32_bf16(af[mi], bfv[ni], acc[mi][ni], 0, 0, 0);
    if (doG) {
      short8 ag[4], bg2[4];
      #pragma unroll
      for (int mi = 0; mi < 4; mi++) ag[mi] = frag_sw(&Cs[1][0], wic * 64 + mi * 16 + fr, q8);
      #pragma unroll
      for (int ni = 0; ni < 4; ni++) bg2[ni] = frag_sw(&As[1][0], wpx * 64 + ni * 16 + fr, q8);
      #pragma unroll
      for (int mi = 0; mi < 4; mi++)
        #pragma unroll
        for (int ni = 0; ni < 4; ni++)
          accg[mi][ni] = __builtin_amdgcn_mfma_f32_16x16x32_bf16(ag[mi], bg2[ni], accg[mi][ni], 0, 0, 0);
    }
  }

  // ---- theta/phi epilogue
  const int colic = wic * 64 + fr;
  float cb[4];
  #pragma unroll
  for (int ni = 0; ni < 4; ni++) cb[ni] = bias[colic + ni * 16];
  #pragma unroll
  for (int mi = 0; mi < 4; mi++)
    #pragma unroll
    for (int r = 0; r < 4; r++) {
      const long m = m0 + wpx * 64 + mi * 16 + (ln >> 4) * 4 + r;
      #pragma unroll
      for (int ni = 0; ni < 4; ni++)
        TPT2[m * 256 + colic + ni * 16] = f2bf(acc[mi][ni][r] + cb[ni]);
    }

  // ---- G epilogue (x-blocks): G[ic][px] per image
  if (doG) {
    const int colpx = px0 + wpx * 64 + fr;
    #pragma unroll
    for (int mi = 0; mi < 4; mi++)
      #pragma unroll
      for (int r = 0; r < 4; r++) {
        const int ic = wic * 64 + mi * 16 + (ln >> 4) * 4 + r;
        const float badd = bg[ic];
        #pragma unroll
        for (int ni = 0; ni < 4; ni++)
          G[((long)img << 20) + (long)ic * 4096 + colpx + ni * 16] = f2bf(accg[mi][ni][r] + badd);
      }
  }
}

// ---------------- scores v3: 3-deep counted pipeline -----------------------
__global__ __launch_bounds__(256)
void scores_k(const short* __restrict__ TT2, const short* __restrict__ PT2,
              short* __restrict__ ST, float* __restrict__ pstats)
{
  __shared__ __align__(16) short As[3][128 * 32];
  __shared__ __align__(16) short Bs[3][128 * 32];
  const int bz = blockIdx.z, by = blockIdx.y, bx = blockIdx.x;
  const int t = threadIdx.x;
  const int wv = t >> 6, ln = t & 63;
  const int wm = (wv >> 1) * 64, wn = (wv & 1) * 64;
  const int fr = ln & 15, q8 = (ln >> 4) * 8;
  const int rowA = t >> 2;
  const int kcs = ((t & 3) ^ ((t >> 4) & 3)) * 8;

  const short* Abase = TT2 + ((long)(bz * 4096 + by * 128)) * 256;
  const short* Bbase = PT2 + ((long)(bz * 4096 + bx * 128)) * 256;

  f32x4 acc[4][4];
  #pragma unroll
  for (int i = 0; i < 4; i++)
    #pragma unroll
    for (int j = 0; j < 4; j++)
      #pragma unroll
      for (int r = 0; r < 4; r++) acc[i][j][r] = 0.f;

  // tile s (0..15): h = s>>3 selects folded half, kk = (s&7)*32; 4 loads/thr
  #define SC_STAGE(s, buf)                                                     \
    {                                                                          \
      const long hoff = (long)((s) >> 3) * 2048 * 256;                         \
      const int kk = ((s) & 7) * 32;                                           \
      _Pragma("unroll")                                                        \
      for (int sv = 0; sv < 2; sv++) {                                         \
        async_ld16(Abase + hoff + (long)(sv * 64 + rowA) * 256 + kk + kcs,     \
                   &As[buf][0] + (sv * 256 + wv * 64) * 8);                    \
        async_ld16(Bbase + hoff + (long)(sv * 64 + rowA) * 256 + kk + kcs,     \
                   &Bs[buf][0] + (sv * 256 + wv * 64) * 8);                    \
      }                                                                        \
    }

  #define SC_COMPUTE(cbuf)                                                     \
    {                                                                          \
      const short* Ac = &As[cbuf][0];                                          \
      const short* Bc = &Bs[cbuf][0];                                          \
      short8 af[4], bfr[4];                                                    \
      _Pragma("unroll")                                                        \
      for (int mi = 0; mi < 4; mi++) af[mi] = frag_sw(Ac, wm + mi * 16 + fr, q8); \
      _Pragma("unroll")                                                        \
      for (int ni = 0; ni < 4; ni++) bfr[ni] = frag_sw(Bc, wn + ni * 16 + fr, q8); \
      _Pragma("unroll")                                                        \
      for (int mi = 0; mi < 4; mi++)                                           \
        _Pragma("unroll")                                                      \
        for (int ni = 0; ni < 4; ni++)                                         \
          acc[mi][ni] = __builtin_amdgcn_mfma_f32_16x16x32_bf16(               \
              af[mi], bfr[ni], acc[mi][ni], 0, 0, 0);                          \
    }

  SC_STAGE(0, 0);
  SC_STAGE(1, 1);
  CBAR(4)

  int cs = 0, ss = 2;
  for (int s = 0; s < 14; s++) {
    SC_STAGE(s + 2, ss);
    SC_COMPUTE(cs);
    CBAR(4)
    cs = (cs == 2) ? 0 : cs + 1;
    ss = (ss == 2) ? 0 : ss + 1;
  }
  SC_COMPUTE(2)                 // tile 14 (14%3==2)
  CBAR(0)
  SC_COMPUTE(0)                 // tile 15 (15%3==0)
  #undef SC_STAGE
  #undef SC_COMPUTE

  const int colb = bx * 128 + wn + fr;
  const int rowb = by * 128 + wm + (ln >> 4) * 4;
  short* base = ST + ((long)bz << 22);
  float ps[4] = {0.f, 0.f, 0.f, 0.f};
  #pragma unroll
  for (int mi = 0; mi < 4; mi++)
    #pragma unroll
    for (int r = 0; r < 4; r++) {
      const long mr = rowb + mi * 16 + r;
      #pragma unroll
      for (int ni = 0; ni < 4; ni++) {
        float e = __expf(acc[mi][ni][r]);
        base[mr * 2048 + colb + ni * 16] = f2bf(e);
        ps[ni] += e;
      }
    }
  #pragma unroll
  for (int ni = 0; ni < 4; ni++) {
    ps[ni] += __shfl_xor(ps[ni], 16);
    ps[ni] += __shfl_xor(ps[ni], 32);
  }
  float* part = (float*)&As[1][0];   // As[1] last read at tile 13 (pre-CBAR)
  if (ln < 16) {
    #pragma unroll
    for (int ni = 0; ni < 4; ni++)
      part[(wv >> 1) * 128 + wn + ni * 16 + fr] = ps[ni];
  }
  __syncthreads();
  if (t < 128)
    pstats[((long)(bz * 16 + by)) * 2048 + bx * 128 + t] = part[t] + part[128 + t];
}

// ---------------- reduce 16 partials -> invZ per column --------------------
__global__ __launch_bounds__(256)
void zfinal(const float* __restrict__ pstats, float* __restrict__ invZ)
{
  const int g = blockIdx.x * 256 + threadIdx.x;
  const int b = g >> 11, col = g & 2047;
  float S = 0.f;
  #pragma unroll
  for (int rc = 0; rc < 16; rc++) S += pstats[((long)(b * 16 + rc)) * 2048 + col];
  invZ[g] = 1.f / S;
}

// ---------------- G *= invZ[m] (in place) ----------------------------------
__global__ __launch_bounds__(256)
void g_scale(short* __restrict__ G, const float* __restrict__ invZ)
{
  const long base = ((long)blockIdx.x * 256 + threadIdx.x) * 8;
  const int bz = (int)(base >> 20);
  const int n2 = (int)(base & 4095);
  const float* z = invZ + bz * 2048 + (n2 & 2047);
  short8 v = *(short8*)&G[base];
  f32x4 z0 = *(const f32x4*)z;
  f32x4 z1 = *(const f32x4*)(z + 4);
  #pragma unroll
  for (int j = 0; j < 4; j++) { v[j] = f2bf(bf2f(v[j]) * z0[j]); v[4 + j] = f2bf(bf2f(v[4 + j]) * z1[j]); }
  *(short8*)&G[base] = v;
}

// ---------------- mask GEMM v3: 3-deep counted pipeline --------------------
__global__ __launch_bounds__(256)
void mask_k(const short* __restrict__ Wm20, const short* __restrict__ Wm21,
            const short* __restrict__ OVT, const float* __restrict__ bmask,
            const float* __restrict__ x, float* __restrict__ out)
{
  __shared__ __align__(16) short As[3][128 * 32];
  __shared__ __align__(16) short Bs[3][128 * 32];
  const int bz = blockIdx.z;
  const int n0 = blockIdx.x * 128;
  const int m0 = blockIdx.y * 128;
  const short* A = (n0 >= 2048) ? Wm21 : Wm20;
  const short* B = OVT + ((long)bz << 20) + (long)(n0 & 2047) * 512;
  const int t = threadIdx.x;
  const int wv = t >> 6, ln = t & 63;
  const int wm = (wv >> 1) * 64, wn = (wv & 1) * 64;
  const int fr = ln & 15, q8 = (ln >> 4) * 8;
  const int rowA = t >> 2;
  const int kcs = ((t & 3) ^ ((t >> 4) & 3)) * 8;

  f32x4 acc[4][4];
  #pragma unroll
  for (int i = 0; i < 4; i++)
    #pragma unroll
    for (int j = 0; j < 4; j++)
      #pragma unroll
      for (int r = 0; r < 4; r++) acc[i][j][r] = 0.f;

  #define MK_STAGE(s, buf)                                                     \
    {                                                                          \
      const int kk = (s) * 32;                                                 \
      _Pragma("unroll")                                                        \
      for (int sv = 0; sv < 2; sv++) {                                         \
        async_ld16(A + (long)(m0 + sv * 64 + rowA) * 512 + kk + kcs,           \
                   &As[buf][0] + (sv * 256 + wv * 64) * 8);                    \
        async_ld16(B + (long)(sv * 64 + rowA) * 512 + kk + kcs,                \
                   &Bs[buf][0] + (sv * 256 + wv * 64) * 8);                    \
      }                                                                        \
    }

  #define MK_COMPUTE(cbuf)                                                     \
    {                                                                          \
      const short* Ac = &As[cbuf][0];                                          \
      const short* Bc = &Bs[cbuf][0];                                          \
      short8 af[4], bfr[4];                                                    \
      _Pragma("unroll")                                                        \
      for (int mi = 0; mi < 4; mi++) af[mi] = frag_sw(Ac, wm + mi * 16 + fr, q8); \
      _Pragma("unroll")                                                        \
      for (int ni = 0; ni < 4; ni++) bfr[ni] = frag_sw(Bc, wn + ni * 16 + fr, q8); \
      _Pragma("unroll")                                                        \
      for (int mi = 0; mi < 4; mi++)                                           \
        _Pragma("unroll")                                                      \
        for (int ni = 0; ni < 4; ni++)                                         \
          acc[mi][ni] = __builtin_amdgcn_mfma_f32_16x16x32_bf16(               \
              af[mi], bfr[ni], acc[mi][ni], 0, 0, 0);                          \
    }

  MK_STAGE(0, 0);
  MK_STAGE(1, 1);
  CBAR(4)

  int cs = 0, ss = 2;
  for (int s = 0; s < 14; s++) {
    MK_STAGE(s + 2, ss);
    MK_COMPUTE(cs);
    CBAR(4)
    cs = (cs == 2) ? 0 : cs + 1;
    ss = (ss == 2) ? 0 : ss + 1;
  }
  MK_COMPUTE(2)                 // tile 14
  CBAR(0)
  MK_COMPUTE(0)                 // tile 15
  #undef MK_STAGE
  #undef MK_COMPUTE

  const int colb = n0 + wn + fr;
  const int rowb = m0 + wm + (ln >> 4) * 4;
  #pragma unroll
  for (int mi = 0; mi < 4; mi++)
    #pragma unroll
    for (int r = 0; r < 4; r++) {
      const int mr = rowb + mi * 16 + r;
      const float badd = bmask[mr];
      const long rbase = ((long)bz * 512 + mr) * 4096;
      #pragma unroll
      for (int ni = 0; ni < 4; ni++) {
        const int cc = colb + ni * 16;
        out[rbase + cc] = acc[mi][ni][r] + badd + x[rbase + cc];
      }
    }
}

// ---------------- weight prep ----------------------------------------------
__global__ __launch_bounds__(256)
void wconv2(const float* w_phi, const float* w_theta, const float* w_g,
            const float* w_mask,
            short* wph, short* wth, short* wg, short* Wm20, short* Wm21)
{
  const int seg = blockIdx.x >> 6;
  const int blk = blockIdx.x & 63;
  const int i0 = blk * 2048 + threadIdx.x * 8;
  if (seg < 3) {
    const float* s = seg == 0 ? w_phi : seg == 1 ? w_theta : w_g;
    short* d = seg == 0 ? wph : seg == 1 ? wth : wg;
    f32x4 a = *(const f32x4*)&s[i0];
    f32x4 b = *(const f32x4*)&s[i0 + 4];
    short8 o;
    #pragma unroll
    for (int j = 0; j < 4; j++) { o[j] = f2bf(a[j]); o[4 + j] = f2bf(b[j]); }
    *(short8*)&d[i0] = o;
  } else {
    const int o = i0 >> 8;
    f32x4 a = *(const f32x4*)&w_mask[i0];
    f32x4 b = *(const f32x4*)&w_mask[i0 + 4];
    short v[8];
    #pragma unroll
    for (int j = 0; j < 4; j++) { v[j] = f2bf(a[j]); v[4 + j] = f2bf(b[j]); }
    short8 a0, a1, b0, b1;
    #pragma unroll
    for (int j = 0; j < 4; j++) {
      a0[2 * j] = v[j];     a0[2 * j + 1] = 0;
      a1[2 * j] = v[4 + j]; a1[2 * j + 1] = 0;
      b0[2 * j] = 0;        b0[2 * j + 1] = v[j];
      b1[2 * j] = 0;        b1[2 * j + 1] = v[4 + j];
    }
    const long base = (long)o * 512 + 2 * (i0 & 255);
    *(short8*)&Wm20[base] = a0; *(short8*)&Wm20[base + 8] = a1;
    *(short8*)&Wm21[base] = b0; *(short8*)&Wm21[base + 8] = b1;
  }
}

// ---------------------------------------------------------------------------
extern "C" void kernel_launch(void* const* d_in, const int* in_sizes, int n_in,
                              void* d_out, int out_size, void* d_ws, size_t ws_size,
                              hipStream_t stream)
{
  (void)in_sizes; (void)n_in; (void)out_size; (void)ws_size;
  const float* x       = (const float*)d_in[0];
  const float* y       = (const float*)d_in[1];
  const float* w_phi   = (const float*)d_in[2];
  const float* b_phi   = (const float*)d_in[3];
  const float* w_theta = (const float*)d_in[4];
  const float* b_theta = (const float*)d_in[5];
  const float* w_g     = (const float*)d_in[6];
  const float* b_g     = (const float*)d_in[7];
  const float* w_mask  = (const float*)d_in[8];
  const float* b_mask  = (const float*)d_in[9];
  float* out = (float*)d_out;

  char* ws = (char*)d_ws;
  const long MB = 1L << 20;
  short* wph  = (short*)(ws + 0);
  short* wth  = (short*)(ws + 256 * 1024);
  short* wg   = (short*)(ws + 512 * 1024);
  short* Wm20 = (short*)(ws + 768 * 1024);
  short* Wm21 = (short*)(ws + 1280 * 1024);
  short* TPT2 = (short*)(ws + 66 * MB);   // [65536][256], 32MB
  short* G    = (short*)(ws + 98 * MB);   // [8][256][4096], 16MB
  short* ST   = (short*)(ws + 2 * MB);    // [8][2048][2048] E, 64MB
  float* pstats = (float*)(ws + 114 * MB);
  float* invZ   = (float*)(ws + 115 * MB);
  short* OVT  = (short*)(ws + 66 * MB);   // [8][2048][512], 16MB (over TPT2)

  dim3 blk(256, 1, 1);
  dim3 blk8(512, 1, 1);

  wconv2<<<dim3(256, 1, 1), blk, 0, stream>>>(w_phi, w_theta, w_g, w_mask,
                                              wph, wth, wg, Wm20, Wm21);

  conv_ptg<<<dim3(512, 1, 1), blk8, 0, stream>>>(x, y, wth, wph, wg,
                                                 b_theta, b_phi, b_g, TPT2, G);

  scores_k<<<dim3(16, 16, 8), blk, 0, stream>>>(TPT2, TPT2 + 32768L * 256, ST, pstats);
  zfinal<<<dim3(64, 1, 1), blk, 0, stream>>>(pstats, invZ);
  g_scale<<<dim3(4096, 1, 1), blk, 0, stream>>>(G, invZ);

  ov_k<<<dim3(512, 1, 1), blk8, 0, stream>>>(ST, G, OVT);

  mask_k<<<dim3(32, 4, 8), blk, 0, stream>>>(Wm20, Wm21, OVT, b_mask, x, out);
}

// Round 10
// 355.807 us; speedup vs baseline: 1.0463x; 1.0044x over previous
//
#include <hip/hip_runtime.h>
#include <hip/hip_bf16.h>

// Non-local block, B=8 C=512 H=W=64, IC=256, N2=HW=4096, N=2048 (folded).
//
// Round-13: XCD co-location remaps (bijective block-id maps only; inner loops
// identical to round 12):
//  - mask_k: XCD i owns image i; 32 bx-blocks of one 128-row band adjacent ->
//    512B out/x row-fragments merge into full 16KB rows in ONE L2.
//  - scores_k: XCD i owns image i; 16 bx of a row-band share the A-tile and
//    merge ST row writes.
//  - conv_ptg: XCD i gets img-i x-slabs then img-i y-slabs; all slabs of a
//    k-step read different 512B chunks of the SAME rows -> rows assembled
//    once in one L2 (attacks the ~1.1 TB/s strided-read wall).
// ov_k keeps its (already co-located) map. Pipelines unchanged.

typedef __attribute__((ext_vector_type(8))) short short8;
typedef __attribute__((ext_vector_type(4))) short short4v;
typedef __attribute__((ext_vector_type(4))) float f32x4;

__device__ __forceinline__ short f2bf(float f) {
  union { __hip_bfloat16 h; short s; } u; u.h = __float2bfloat16(f); return u.s;
}
__device__ __forceinline__ float bf2f(short s) {
  union { short s; __hip_bfloat16 h; } u; u.s = s; return __bfloat162float(u.h);
}

__device__ __forceinline__ void async_ld16(const void* g, void* l) {
  __builtin_amdgcn_global_load_lds(
      (const __attribute__((address_space(1))) unsigned int*)(unsigned long long)g,
      (__attribute__((address_space(3))) unsigned int*)(unsigned int)(unsigned long long)l,
      16, 0, 0);
}

// counted barrier: drain all but the newest N outstanding vmem ops, all LDS ops
#define CBAR(N)                                                                \
  asm volatile("s_waitcnt vmcnt(" #N ") lgkmcnt(0)" ::: "memory");             \
  __builtin_amdgcn_s_barrier();

// swizzled b128 fragment read from a [row][32-short] tile whose 16B-unit u
// holds global chunk u ^ ((row>>2)&3)
__device__ __forceinline__ short8 frag_sw(const short* Ds, int row, int q8)
{
  return *(const short8*)&Ds[row * 32 + (((q8 >> 3) ^ ((row >> 2) & 3)) << 3)];
}

// ---------------- OV GEMM v3: 3-deep counted pipeline ----------------------
// OVT[b][n][c] = sum_m E[n][m]*G''[c][m]. 512 blocks; XCD-local slab map.
__global__ __launch_bounds__(512, 4)
void ov_k(const short* __restrict__ Eg, const short* __restrict__ Gg,
          short* __restrict__ Cg)
{
  const int L = blockIdx.x;
  const int xcd = L & 7, k = L >> 3;
  const int slab = xcd + ((k >> 2) << 3);   // 0..127
  const int bz = slab >> 4, by = slab & 15, bx = k & 3;

  __shared__ __align__(16) short As[3][128 * 32];
  __shared__ __align__(16) short Bs[3][128 * 32];
  const short* A = Eg + ((long)bz << 22);
  const short* B = Gg + ((long)bz << 20);
  const int m0 = by * 128;
  const int n0 = bx * 128;
  const int t = threadIdx.x;
  const int wv = t >> 6, ln = t & 63;
  const int wr = wv >> 1, wc = wv & 1;
  const int fr = ln & 15, q8 = (ln >> 4) * 8;
  const int rowA = t >> 2;
  const int kcs = ((t & 3) ^ ((t >> 4) & 3)) * 8;   // inverse-swizzled source chunk

  f32x4 acc[2][4];
  #pragma unroll
  for (int i = 0; i < 2; i++)
    #pragma unroll
    for (int j = 0; j < 4; j++)
      #pragma unroll
      for (int r = 0; r < 4; r++) acc[i][j][r] = 0.f;

  #define OV_STAGE(kt, buf)                                                    \
    async_ld16(A + (long)(m0 + rowA) * 2048 + (kt) * 32 + kcs,                 \
               &As[buf][0] + wv * 512);                                        \
    async_ld16(B + (long)(n0 + rowA) * 2048 + (kt) * 32 + kcs,                 \
               &Bs[buf][0] + wv * 512);

  #define OV_COMPUTE(cbuf)                                                     \
    {                                                                          \
      const short* Ac = &As[cbuf][0];                                          \
      const short* Bc = &Bs[cbuf][0];                                          \
      short8 af[2], bfr[4];                                                    \
      _Pragma("unroll")                                                        \
      for (int mi = 0; mi < 2; mi++)                                           \
        af[mi] = frag_sw(Ac, wr * 32 + mi * 16 + fr, q8);                      \
      _Pragma("unroll")                                                        \
      for (int ni = 0; ni < 4; ni++)                                           \
        bfr[ni] = frag_sw(Bc, wc * 64 + ni * 16 + fr, q8);                     \
      _Pragma("unroll")                                                        \
      for (int mi = 0; mi < 2; mi++)                                           \
        _Pragma("unroll")                                                      \
        for (int ni = 0; ni < 4; ni++)                                         \
          acc[mi][ni] = __builtin_amdgcn_mfma_f32_16x16x32_bf16(               \
              af[mi], bfr[ni], acc[mi][ni], 0, 0, 0);                          \
    }

  OV_STAGE(0, 0);
  OV_STAGE(1, 1);
  CBAR(2)                       // drain tile-0 batch; tile-1 stays in flight

  int cs = 0, ss = 2;
  for (int kt = 0; kt < 62; kt++) {
    OV_STAGE(kt + 2, ss);
    OV_COMPUTE(cs);
    CBAR(2)                     // drain tile-(kt+1) batch; tile-(kt+2) flies
    cs = (cs == 2) ? 0 : cs + 1;
    ss = (ss == 2) ? 0 : ss + 1;
  }
  OV_COMPUTE(2)                 // tile 62 (62%3==2)
  CBAR(0)                       // drain tile-63 batch
  OV_COMPUTE(0)                 // tile 63 (63%3==0)
  #undef OV_STAGE
  #undef OV_COMPUTE

  const int colb = n0 + wc * 64 + fr;
  const int rowb = m0 + wr * 32 + (ln >> 4) * 4;
  #pragma unroll
  for (int mi = 0; mi < 2; mi++)
    #pragma unroll
    for (int r = 0; r < 4; r++) {
      const int mr = rowb + mi * 16 + r;
      #pragma unroll
      for (int ni = 0; ni < 4; ni++)
        Cg[((long)bz << 20) + (long)mr * 512 + colb + ni * 16] = f2bf(acc[mi][ni][r]);
    }
}

// ---------------- fused theta/phi conv + G: one staging of x ---------------
// XCD map: L -> xcd = L&7, k = L>>3 (0..63). XCD i runs img-i x-slabs
// (k<32, all 32 px windows co-resident) then img-i y-slabs. All slabs of a
// k-step read different 512B chunks of the same 16KB rows -> L2-row-merged.
__global__ __launch_bounds__(512, 2)
void conv_ptg(const float* __restrict__ x, const float* __restrict__ y,
              const short* __restrict__ wth, const short* __restrict__ wph,
              const short* __restrict__ wg,
              const float* __restrict__ bth, const float* __restrict__ bph,
              const float* __restrict__ bg,
              short* __restrict__ TPT2, short* __restrict__ G)
{
  __shared__ __align__(16) short As[2][128 * 32];   // img [px][32c], swizzled
  __shared__ __align__(16) short Bs[2][256 * 32];   // wth/wph, swizzled
  __shared__ __align__(16) short Cs[2][256 * 32];   // wg, swizzled (x-blocks)
  const int L = blockIdx.x;
  const int xcd = L & 7, kk2 = L >> 3;              // kk2: 0..63
  const int slab = (kk2 >> 5) * 256 + xcd * 32 + (kk2 & 31);  // bijective
  const bool isphi = slab >= 256;
  const bool doG = !isphi;
  const int s2 = slab & 255;
  const int img = s2 >> 5;
  const float* src = (isphi ? y : x) + (long)img * (512L * 4096);
  const int px0 = (s2 & 31) * 128;
  const long m0 = (long)slab * 128;
  const short* W = isphi ? wph : wth;
  const float* bias = isphi ? bph : bth;
  const int t = threadIdx.x;
  const int wv = t >> 6, ln = t & 63;
  const int wpx = wv >> 2, wic = wv & 3;            // theta: [wpx*64 px][wic*64 ic]
  const int fr = ln & 15, q8 = (ln >> 4) * 8;
  const int g4 = (t >> 5) * 4, p4 = (t & 31) * 4;   // img stager coords
  const int w2 = wv - 4;                            // weight stager wave
  const int kcs = ((ln & 3) ^ (ln >> 4)) * 8;       // weight source swizzle

  f32x4 acc[4][4], accg[4][4];
  #pragma unroll
  for (int i = 0; i < 4; i++)
    #pragma unroll
    for (int j = 0; j < 4; j++)
      #pragma unroll
      for (int r = 0; r < 4; r++) { acc[i][j][r] = 0.f; accg[i][j][r] = 0.f; }

  // ---- prologue: fill buffer 0 (k-step 0)
  if (t >= 256) {
    #pragma unroll
    for (int j = 0; j < 4; j++)
      async_ld16(W + (long)(w2 * 64 + j * 16 + (ln >> 2)) * 512 + kcs,
                 &Bs[0][(w2 * 64 + j * 16) * 32]);
    if (doG) {
      #pragma unroll
      for (int j = 0; j < 4; j++)
        async_ld16(wg + (long)(w2 * 64 + j * 16 + (ln >> 2)) * 512 + kcs,
                   &Cs[0][(w2 * 64 + j * 16) * 32]);
    }
  } else {
    f32x4 r[4];
    #pragma unroll
    for (int i = 0; i < 4; i++)
      r[i] = *(const f32x4*)&src[(long)(g4 + i) * 4096 + px0 + p4];
    #pragma unroll
    for (int j = 0; j < 4; j++) {
      short4v w;
      w[0] = f2bf(r[0][j]); w[1] = f2bf(r[1][j]); w[2] = f2bf(r[2][j]); w[3] = f2bf(r[3][j]);
      const int px = p4 + j;
      const int u = (g4 >> 3) ^ ((px >> 2) & 3);
      *(short4v*)&As[0][px * 32 + u * 8 + (g4 & 4)] = w;
    }
  }
  __syncthreads();

  // ---- main loop: compute k-1 while staging k
  for (int k = 1; k < 16; k++) {
    const int cur = (k - 1) & 1, nxt = k & 1;
    f32x4 r[4];
    if (t >= 256) {
      #pragma unroll
      for (int j = 0; j < 4; j++)
        async_ld16(W + (long)(w2 * 64 + j * 16 + (ln >> 2)) * 512 + k * 32 + kcs,
                   &Bs[nxt][(w2 * 64 + j * 16) * 32]);
      if (doG) {
        #pragma unroll
        for (int j = 0; j < 4; j++)
          async_ld16(wg + (long)(w2 * 64 + j * 16 + (ln >> 2)) * 512 + k * 32 + kcs,
                     &Cs[nxt][(w2 * 64 + j * 16) * 32]);
      }
    } else {
      #pragma unroll
      for (int i = 0; i < 4; i++)
        r[i] = *(const f32x4*)&src[(long)(k * 32 + g4 + i) * 4096 + px0 + p4];
    }
    short8 af[4], bfv[4];
    #pragma unroll
    for (int mi = 0; mi < 4; mi++) af[mi] = frag_sw(&As[cur][0], wpx * 64 + mi * 16 + fr, q8);
    #pragma unroll
    for (int ni = 0; ni < 4; ni++) bfv[ni] = frag_sw(&Bs[cur][0], wic * 64 + ni * 16 + fr, q8);
    #pragma unroll
    for (int mi = 0; mi < 4; mi++)
      #pragma unroll
      for (int ni = 0; ni < 4; ni++)
        acc[mi][ni] = __builtin_amdgcn_mfma_f32_16x16x32_bf16(af[mi], bfv[ni], acc[mi][ni], 0, 0, 0);
    if (doG) {
      short8 ag[4], bg2[4];
      #pragma unroll
      for (int mi = 0; mi < 4; mi++) ag[mi] = frag_sw(&Cs[cur][0], wic * 64 + mi * 16 + fr, q8);
      #pragma unroll
      for (int ni = 0; ni < 4; ni++) bg2[ni] = frag_sw(&As[cur][0], wpx * 64 + ni * 16 + fr, q8);
      #pragma unroll
      for (int mi = 0; mi < 4; mi++)
        #pragma unroll
        for (int ni = 0; ni < 4; ni++)
          accg[mi][ni] = __builtin_amdgcn_mfma_f32_16x16x32_bf16(ag[mi], bg2[ni], accg[mi][ni], 0, 0, 0);
    }
    if (t < 256) {
      #pragma unroll
      for (int j = 0; j < 4; j++) {
        short4v w;
        w[0] = f2bf(r[0][j]); w[1] = f2bf(r[1][j]); w[2] = f2bf(r[2][j]); w[3] = f2bf(r[3][j]);
        const int px = p4 + j;
        const int u = (g4 >> 3) ^ ((px >> 2) & 3);
        *(short4v*)&As[nxt][px * 32 + u * 8 + (g4 & 4)] = w;
      }
    }
    __syncthreads();
  }

  // ---- final k-step (buffer 1)
  {
    short8 af[4], bfv[4];
    #pragma unroll
    for (int mi = 0; mi < 4; mi++) af[mi] = frag_sw(&As[1][0], wpx * 64 + mi * 16 + fr, q8);
    #pragma unroll
    for (int ni = 0; ni < 4; ni++) bfv[ni] = frag_sw(&Bs[1][0], wic * 64 + ni * 16 + fr, q8);
    #pragma unroll
    for (int mi = 0; mi < 4; mi++)
      #pragma unroll
      for (int ni = 0; ni < 4; ni++)
        acc[mi][ni] = __builtin_amdgcn_mfma_f32_16x16x32_bf16(af[mi], bfv[ni], acc[mi][ni], 0, 0, 0);
    if (doG) {
      short8 ag[4], bg2[4];
      #pragma unroll
      for (int mi = 0; mi < 4; mi++) ag[mi] = frag_sw(&Cs[1][0], wic * 64 + mi * 16 + fr, q8);
      #pragma unroll
      for (int ni = 0; ni < 4; ni++) bg2[ni] = frag_sw(&As[1][0], wpx * 64 + ni * 16 + fr, q8);
      #pragma unroll
      for (int mi = 0; mi < 4; mi++)
        #pragma unroll
        for (int ni = 0; ni < 4; ni++)
          accg[mi][ni] = __builtin_amdgcn_mfma_f32_16x16x32_bf16(ag[mi], bg2[ni], accg[mi][ni], 0, 0, 0);
    }
  }

  // ---- theta/phi epilogue
  const int colic = wic * 64 + fr;
  float cb[4];
  #pragma unroll
  for (int ni = 0; ni < 4; ni++) cb[ni] = bias[colic + ni * 16];
  #pragma unroll
  for (int mi = 0; mi < 4; mi++)
    #pragma unroll
    for (int r = 0; r < 4; r++) {
      const long m = m0 + wpx * 64 + mi * 16 + (ln >> 4) * 4 + r;
      #pragma unroll
      for (int ni = 0; ni < 4; ni++)
        TPT2[m * 256 + colic + ni * 16] = f2bf(acc[mi][ni][r] + cb[ni]);
    }

  // ---- G epilogue (x-blocks): G[ic][px] per image
  if (doG) {
    const int colpx = px0 + wpx * 64 + fr;
    #pragma unroll
    for (int mi = 0; mi < 4; mi++)
      #pragma unroll
      for (int r = 0; r < 4; r++) {
        const int ic = wic * 64 + mi * 16 + (ln >> 4) * 4 + r;
        const float badd = bg[ic];
        #pragma unroll
        for (int ni = 0; ni < 4; ni++)
          G[((long)img << 20) + (long)ic * 4096 + colpx + ni * 16] = f2bf(accg[mi][ni][r] + badd);
      }
  }
}

// ---------------- scores v3: 3-deep counted pipeline, XCD-colocated --------
// Map: XCD i owns image i (256 blocks); the 16 bx-blocks of one row-band run
// adjacently (share the A-tile; ST row-fragments merge in L2).
__global__ __launch_bounds__(256)
void scores_k(const short* __restrict__ TT2, const short* __restrict__ PT2,
              short* __restrict__ ST, float* __restrict__ pstats)
{
  __shared__ __align__(16) short As[3][128 * 32];
  __shared__ __align__(16) short Bs[3][128 * 32];
  const int L = blockIdx.x;
  const int xcd = L & 7, kb = L >> 3;          // kb: 0..255
  const int grp = xcd * 16 + (kb >> 4);        // 0..127
  const int bz = grp >> 4, by = grp & 15, bx = kb & 15;
  const int t = threadIdx.x;
  const int wv = t >> 6, ln = t & 63;
  const int wm = (wv >> 1) * 64, wn = (wv & 1) * 64;
  const int fr = ln & 15, q8 = (ln >> 4) * 8;
  const int rowA = t >> 2;
  const int kcs = ((t & 3) ^ ((t >> 4) & 3)) * 8;

  const short* Abase = TT2 + ((long)(bz * 4096 + by * 128)) * 256;
  const short* Bbase = PT2 + ((long)(bz * 4096 + bx * 128)) * 256;

  f32x4 acc[4][4];
  #pragma unroll
  for (int i = 0; i < 4; i++)
    #pragma unroll
    for (int j = 0; j < 4; j++)
      #pragma unroll
      for (int r = 0; r < 4; r++) acc[i][j][r] = 0.f;

  // tile s (0..15): h = s>>3 selects folded half, kk = (s&7)*32; 4 loads/thr
  #define SC_STAGE(s, buf)                                                     \
    {                                                                          \
      const long hoff = (long)((s) >> 3) * 2048 * 256;                         \
      const int kk = ((s) & 7) * 32;                                           \
      _Pragma("unroll")                                                        \
      for (int sv = 0; sv < 2; sv++) {                                         \
        async_ld16(Abase + hoff + (long)(sv * 64 + rowA) * 256 + kk + kcs,     \
                   &As[buf][0] + (sv * 256 + wv * 64) * 8);                    \
        async_ld16(Bbase + hoff + (long)(sv * 64 + rowA) * 256 + kk + kcs,     \
                   &Bs[buf][0] + (sv * 256 + wv * 64) * 8);                    \
      }                                                                        \
    }

  #define SC_COMPUTE(cbuf)                                                     \
    {                                                                          \
      const short* Ac = &As[cbuf][0];                                          \
      const short* Bc = &Bs[cbuf][0];                                          \
      short8 af[4], bfr[4];                                                    \
      _Pragma("unroll")                                                        \
      for (int mi = 0; mi < 4; mi++) af[mi] = frag_sw(Ac, wm + mi * 16 + fr, q8); \
      _Pragma("unroll")                                                        \
      for (int ni = 0; ni < 4; ni++) bfr[ni] = frag_sw(Bc, wn + ni * 16 + fr, q8); \
      _Pragma("unroll")                                                        \
      for (int mi = 0; mi < 4; mi++)                                           \
        _Pragma("unroll")                                                      \
        for (int ni = 0; ni < 4; ni++)                                         \
          acc[mi][ni] = __builtin_amdgcn_mfma_f32_16x16x32_bf16(               \
              af[mi], bfr[ni], acc[mi][ni], 0, 0, 0);                          \
    }

  SC_STAGE(0, 0);
  SC_STAGE(1, 1);
  CBAR(4)

  int cs = 0, ss = 2;
  for (int s = 0; s < 14; s++) {
    SC_STAGE(s + 2, ss);
    SC_COMPUTE(cs);
    CBAR(4)
    cs = (cs == 2) ? 0 : cs + 1;
    ss = (ss == 2) ? 0 : ss + 1;
  }
  SC_COMPUTE(2)                 // tile 14 (14%3==2)
  CBAR(0)
  SC_COMPUTE(0)                 // tile 15 (15%3==0)
  #undef SC_STAGE
  #undef SC_COMPUTE

  const int colb = bx * 128 + wn + fr;
  const int rowb = by * 128 + wm + (ln >> 4) * 4;
  short* base = ST + ((long)bz << 22);
  float ps[4] = {0.f, 0.f, 0.f, 0.f};
  #pragma unroll
  for (int mi = 0; mi < 4; mi++)
    #pragma unroll
    for (int r = 0; r < 4; r++) {
      const long mr = rowb + mi * 16 + r;
      #pragma unroll
      for (int ni = 0; ni < 4; ni++) {
        float e = __expf(acc[mi][ni][r]);
        base[mr * 2048 + colb + ni * 16] = f2bf(e);
        ps[ni] += e;
      }
    }
  #pragma unroll
  for (int ni = 0; ni < 4; ni++) {
    ps[ni] += __shfl_xor(ps[ni], 16);
    ps[ni] += __shfl_xor(ps[ni], 32);
  }
  float* part = (float*)&As[1][0];
  if (ln < 16) {
    #pragma unroll
    for (int ni = 0; ni < 4; ni++)
      part[(wv >> 1) * 128 + wn + ni * 16 + fr] = ps[ni];
  }
  __syncthreads();
  if (t < 128)
    pstats[((long)(bz * 16 + by)) * 2048 + bx * 128 + t] = part[t] + part[128 + t];
}

// ---------------- reduce 16 partials -> invZ per column --------------------
__global__ __launch_bounds__(256)
void zfinal(const float* __restrict__ pstats, float* __restrict__ invZ)
{
  const int g = blockIdx.x * 256 + threadIdx.x;
  const int b = g >> 11, col = g & 2047;
  float S = 0.f;
  #pragma unroll
  for (int rc = 0; rc < 16; rc++) S += pstats[((long)(b * 16 + rc)) * 2048 + col];
  invZ[g] = 1.f / S;
}

// ---------------- G *= invZ[m] (in place) ----------------------------------
__global__ __launch_bounds__(256)
void g_scale(short* __restrict__ G, const float* __restrict__ invZ)
{
  const long base = ((long)blockIdx.x * 256 + threadIdx.x) * 8;
  const int bz = (int)(base >> 20);
  const int n2 = (int)(base & 4095);
  const float* z = invZ + bz * 2048 + (n2 & 2047);
  short8 v = *(short8*)&G[base];
  f32x4 z0 = *(const f32x4*)z;
  f32x4 z1 = *(const f32x4*)(z + 4);
  #pragma unroll
  for (int j = 0; j < 4; j++) { v[j] = f2bf(bf2f(v[j]) * z0[j]); v[4 + j] = f2bf(bf2f(v[4 + j]) * z1[j]); }
  *(short8*)&G[base] = v;
}

// ---------------- mask GEMM v4: 3-deep pipeline, XCD-colocated -------------
// Map (1024 blocks): XCD i owns image i (128 blocks = 4 row-bands x 32
// col-blocks); the 32 bx of one band run adjacently -> their 512B fragments
// of out/x rows merge into full 16KB rows in one L2 (2MB band vs 4MB L2).
__global__ __launch_bounds__(256)
void mask_k(const short* __restrict__ Wm20, const short* __restrict__ Wm21,
            const short* __restrict__ OVT, const float* __restrict__ bmask,
            const float* __restrict__ x, float* __restrict__ out)
{
  __shared__ __align__(16) short As[3][128 * 32];
  __shared__ __align__(16) short Bs[3][128 * 32];
  const int L = blockIdx.x;
  const int xcd = L & 7, kb = L >> 3;          // kb: 0..127
  const int grp = xcd * 4 + (kb >> 5);         // 0..31
  const int bz = grp >> 2, by = grp & 3, bx = kb & 31;
  const int n0 = bx * 128;
  const int m0 = by * 128;
  const short* A = (n0 >= 2048) ? Wm21 : Wm20;
  const short* B = OVT + ((long)bz << 20) + (long)(n0 & 2047) * 512;
  const int t = threadIdx.x;
  const int wv = t >> 6, ln = t & 63;
  const int wm = (wv >> 1) * 64, wn = (wv & 1) * 64;
  const int fr = ln & 15, q8 = (ln >> 4) * 8;
  const int rowA = t >> 2;
  const int kcs = ((t & 3) ^ ((t >> 4) & 3)) * 8;

  f32x4 acc[4][4];
  #pragma unroll
  for (int i = 0; i < 4; i++)
    #pragma unroll
    for (int j = 0; j < 4; j++)
      #pragma unroll
      for (int r = 0; r < 4; r++) acc[i][j][r] = 0.f;

  #define MK_STAGE(s, buf)                                                     \
    {                                                                          \
      const int kk = (s) * 32;                                                 \
      _Pragma("unroll")                                                        \
      for (int sv = 0; sv < 2; sv++) {                                         \
        async_ld16(A + (long)(m0 + sv * 64 + rowA) * 512 + kk + kcs,           \
                   &As[buf][0] + (sv * 256 + wv * 64) * 8);                    \
        async_ld16(B + (long)(sv * 64 + rowA) * 512 + kk + kcs,                \
                   &Bs[buf][0] + (sv * 256 + wv * 64) * 8);                    \
      }                                                                        \
    }

  #define MK_COMPUTE(cbuf)                                                     \
    {                                                                          \
      const short* Ac = &As[cbuf][0];                                          \
      const short* Bc = &Bs[cbuf][0];                                          \
      short8 af[4], bfr[4];                                                    \
      _Pragma("unroll")                                                        \
      for (int mi = 0; mi < 4; mi++) af[mi] = frag_sw(Ac, wm + mi * 16 + fr, q8); \
      _Pragma("unroll")                                                        \
      for (int ni = 0; ni < 4; ni++) bfr[ni] = frag_sw(Bc, wn + ni * 16 + fr, q8); \
      _Pragma("unroll")                                                        \
      for (int mi = 0; mi < 4; mi++)                                           \
        _Pragma("unroll")                                                      \
        for (int ni = 0; ni < 4; ni++)                                         \
          acc[mi][ni] = __builtin_amdgcn_mfma_f32_16x16x32_bf16(               \
              af[mi], bfr[ni], acc[mi][ni], 0, 0, 0);                          \
    }

  MK_STAGE(0, 0);
  MK_STAGE(1, 1);
  CBAR(4)

  int cs = 0, ss = 2;
  for (int s = 0; s < 14; s++) {
    MK_STAGE(s + 2, ss);
    MK_COMPUTE(cs);
    CBAR(4)
    cs = (cs == 2) ? 0 : cs + 1;
    ss = (ss == 2) ? 0 : ss + 1;
  }
  MK_COMPUTE(2)                 // tile 14
  CBAR(0)
  MK_COMPUTE(0)                 // tile 15
  #undef MK_STAGE
  #undef MK_COMPUTE

  const int colb = n0 + wn + fr;
  const int rowb = m0 + wm + (ln >> 4) * 4;
  #pragma unroll
  for (int mi = 0; mi < 4; mi++)
    #pragma unroll
    for (int r = 0; r < 4; r++) {
      const int mr = rowb + mi * 16 + r;
      const float badd = bmask[mr];
      const long rbase = ((long)bz * 512 + mr) * 4096;
      #pragma unroll
      for (int ni = 0; ni < 4; ni++) {
        const int cc = colb + ni * 16;
        out[rbase + cc] = acc[mi][ni][r] + badd + x[rbase + cc];
      }
    }
}

// ---------------- weight prep ----------------------------------------------
__global__ __launch_bounds__(256)
void wconv2(const float* w_phi, const float* w_theta, const float* w_g,
            const float* w_mask,
            short* wph, short* wth, short* wg, short* Wm20, short* Wm21)
{
  const int seg = blockIdx.x >> 6;
  const int blk = blockIdx.x & 63;
  const int i0 = blk * 2048 + threadIdx.x * 8;
  if (seg < 3) {
    const float* s = seg == 0 ? w_phi : seg == 1 ? w_theta : w_g;
    short* d = seg == 0 ? wph : seg == 1 ? wth : wg;
    f32x4 a = *(const f32x4*)&s[i0];
    f32x4 b = *(const f32x4*)&s[i0 + 4];
    short8 o;
    #pragma unroll
    for (int j = 0; j < 4; j++) { o[j] = f2bf(a[j]); o[4 + j] = f2bf(b[j]); }
    *(short8*)&d[i0] = o;
  } else {
    const int o = i0 >> 8;
    f32x4 a = *(const f32x4*)&w_mask[i0];
    f32x4 b = *(const f32x4*)&w_mask[i0 + 4];
    short v[8];
    #pragma unroll
    for (int j = 0; j < 4; j++) { v[j] = f2bf(a[j]); v[4 + j] = f2bf(b[j]); }
    short8 a0, a1, b0, b1;
    #pragma unroll
    for (int j = 0; j < 4; j++) {
      a0[2 * j] = v[j];     a0[2 * j + 1] = 0;
      a1[2 * j] = v[4 + j]; a1[2 * j + 1] = 0;
      b0[2 * j] = 0;        b0[2 * j + 1] = v[j];
      b1[2 * j] = 0;        b1[2 * j + 1] = v[4 + j];
    }
    const long base = (long)o * 512 + 2 * (i0 & 255);
    *(short8*)&Wm20[base] = a0; *(short8*)&Wm20[base + 8] = a1;
    *(short8*)&Wm21[base] = b0; *(short8*)&Wm21[base + 8] = b1;
  }
}

// ---------------------------------------------------------------------------
extern "C" void kernel_launch(void* const* d_in, const int* in_sizes, int n_in,
                              void* d_out, int out_size, void* d_ws, size_t ws_size,
                              hipStream_t stream)
{
  (void)in_sizes; (void)n_in; (void)out_size; (void)ws_size;
  const float* x       = (const float*)d_in[0];
  const float* y       = (const float*)d_in[1];
  const float* w_phi   = (const float*)d_in[2];
  const float* b_phi   = (const float*)d_in[3];
  const float* w_theta = (const float*)d_in[4];
  const float* b_theta = (const float*)d_in[5];
  const float* w_g     = (const float*)d_in[6];
  const float* b_g     = (const float*)d_in[7];
  const float* w_mask  = (const float*)d_in[8];
  const float* b_mask  = (const float*)d_in[9];
  float* out = (float*)d_out;

  char* ws = (char*)d_ws;
  const long MB = 1L << 20;
  short* wph  = (short*)(ws + 0);
  short* wth  = (short*)(ws + 256 * 1024);
  short* wg   = (short*)(ws + 512 * 1024);
  short* Wm20 = (short*)(ws + 768 * 1024);
  short* Wm21 = (short*)(ws + 1280 * 1024);
  short* TPT2 = (short*)(ws + 66 * MB);   // [65536][256], 32MB
  short* G    = (short*)(ws + 98 * MB);   // [8][256][4096], 16MB
  short* ST   = (short*)(ws + 2 * MB);    // [8][2048][2048] E, 64MB
  float* pstats = (float*)(ws + 114 * MB);
  float* invZ   = (float*)(ws + 115 * MB);
  short* OVT  = (short*)(ws + 66 * MB);   // [8][2048][512], 16MB (over TPT2)

  dim3 blk(256, 1, 1);
  dim3 blk8(512, 1, 1);

  wconv2<<<dim3(256, 1, 1), blk, 0, stream>>>(w_phi, w_theta, w_g, w_mask,
                                              wph, wth, wg, Wm20, Wm21);

  conv_ptg<<<dim3(512, 1, 1), blk8, 0, stream>>>(x, y, wth, wph, wg,
                                                 b_theta, b_phi, b_g, TPT2, G);

  scores_k<<<dim3(2048, 1, 1), blk, 0, stream>>>(TPT2, TPT2 + 32768L * 256, ST, pstats);
  zfinal<<<dim3(64, 1, 1), blk, 0, stream>>>(pstats, invZ);
  g_scale<<<dim3(4096, 1, 1), blk, 0, stream>>>(G, invZ);

  ov_k<<<dim3(512, 1, 1), blk8, 0, stream>>>(ST, G, OVT);

  mask_k<<<dim3(1024, 1, 1), blk, 0, stream>>>(Wm20, Wm21, OVT, b_mask, x, out);
}

// Round 11
// 323.700 us; speedup vs baseline: 1.1501x; 1.0992x over previous
//
#include <hip/hip_runtime.h>
#include <hip/hip_bf16.h>

// Non-local block, B=8 C=512 H=W=64, IC=256, N2=HW=4096, N=2048 (folded).
//
// Round-14: mask_k LDS-restaged epilogue. The old epilogue wrote out / read x
// in 64B lane-segments (16 floats x 16 lanes) at 16KB stride -> partial-line
// RMW at L2/HBM, 1.5 TB/s. New: acc -> LDS (two 64-row halves, stride 132
// f32, conflict-free) -> row-major pass where each thread does f32x4 chunks:
// 512B contiguous per row for BOTH the x read and out write. Everything else
// identical to round 13 (XCD maps + depth-3 counted pipelines).

typedef __attribute__((ext_vector_type(8))) short short8;
typedef __attribute__((ext_vector_type(4))) short short4v;
typedef __attribute__((ext_vector_type(4))) float f32x4;

__device__ __forceinline__ short f2bf(float f) {
  union { __hip_bfloat16 h; short s; } u; u.h = __float2bfloat16(f); return u.s;
}
__device__ __forceinline__ float bf2f(short s) {
  union { short s; __hip_bfloat16 h; } u; u.s = s; return __bfloat162float(u.h);
}

__device__ __forceinline__ void async_ld16(const void* g, void* l) {
  __builtin_amdgcn_global_load_lds(
      (const __attribute__((address_space(1))) unsigned int*)(unsigned long long)g,
      (__attribute__((address_space(3))) unsigned int*)(unsigned int)(unsigned long long)l,
      16, 0, 0);
}

// counted barrier: drain all but the newest N outstanding vmem ops, all LDS ops
#define CBAR(N)                                                                \
  asm volatile("s_waitcnt vmcnt(" #N ") lgkmcnt(0)" ::: "memory");             \
  __builtin_amdgcn_s_barrier();

// swizzled b128 fragment read from a [row][32-short] tile whose 16B-unit u
// holds global chunk u ^ ((row>>2)&3)
__device__ __forceinline__ short8 frag_sw(const short* Ds, int row, int q8)
{
  return *(const short8*)&Ds[row * 32 + (((q8 >> 3) ^ ((row >> 2) & 3)) << 3)];
}

// ---------------- OV GEMM v3: 3-deep counted pipeline ----------------------
// OVT[b][n][c] = sum_m E[n][m]*G''[c][m]. 512 blocks; XCD-local slab map.
__global__ __launch_bounds__(512, 4)
void ov_k(const short* __restrict__ Eg, const short* __restrict__ Gg,
          short* __restrict__ Cg)
{
  const int L = blockIdx.x;
  const int xcd = L & 7, k = L >> 3;
  const int slab = xcd + ((k >> 2) << 3);   // 0..127
  const int bz = slab >> 4, by = slab & 15, bx = k & 3;

  __shared__ __align__(16) short As[3][128 * 32];
  __shared__ __align__(16) short Bs[3][128 * 32];
  const short* A = Eg + ((long)bz << 22);
  const short* B = Gg + ((long)bz << 20);
  const int m0 = by * 128;
  const int n0 = bx * 128;
  const int t = threadIdx.x;
  const int wv = t >> 6, ln = t & 63;
  const int wr = wv >> 1, wc = wv & 1;
  const int fr = ln & 15, q8 = (ln >> 4) * 8;
  const int rowA = t >> 2;
  const int kcs = ((t & 3) ^ ((t >> 4) & 3)) * 8;   // inverse-swizzled source chunk

  f32x4 acc[2][4];
  #pragma unroll
  for (int i = 0; i < 2; i++)
    #pragma unroll
    for (int j = 0; j < 4; j++)
      #pragma unroll
      for (int r = 0; r < 4; r++) acc[i][j][r] = 0.f;

  #define OV_STAGE(kt, buf)                                                    \
    async_ld16(A + (long)(m0 + rowA) * 2048 + (kt) * 32 + kcs,                 \
               &As[buf][0] + wv * 512);                                        \
    async_ld16(B + (long)(n0 + rowA) * 2048 + (kt) * 32 + kcs,                 \
               &Bs[buf][0] + wv * 512);

  #define OV_COMPUTE(cbuf)                                                     \
    {                                                                          \
      const short* Ac = &As[cbuf][0];                                          \
      const short* Bc = &Bs[cbuf][0];                                          \
      short8 af[2], bfr[4];                                                    \
      _Pragma("unroll")                                                        \
      for (int mi = 0; mi < 2; mi++)                                           \
        af[mi] = frag_sw(Ac, wr * 32 + mi * 16 + fr, q8);                      \
      _Pragma("unroll")                                                        \
      for (int ni = 0; ni < 4; ni++)                                           \
        bfr[ni] = frag_sw(Bc, wc * 64 + ni * 16 + fr, q8);                     \
      _Pragma("unroll")                                                        \
      for (int mi = 0; mi < 2; mi++)                                           \
        _Pragma("unroll")                                                      \
        for (int ni = 0; ni < 4; ni++)                                         \
          acc[mi][ni] = __builtin_amdgcn_mfma_f32_16x16x32_bf16(               \
              af[mi], bfr[ni], acc[mi][ni], 0, 0, 0);                          \
    }

  OV_STAGE(0, 0);
  OV_STAGE(1, 1);
  CBAR(2)                       // drain tile-0 batch; tile-1 stays in flight

  int cs = 0, ss = 2;
  for (int kt = 0; kt < 62; kt++) {
    OV_STAGE(kt + 2, ss);
    OV_COMPUTE(cs);
    CBAR(2)                     // drain tile-(kt+1) batch; tile-(kt+2) flies
    cs = (cs == 2) ? 0 : cs + 1;
    ss = (ss == 2) ? 0 : ss + 1;
  }
  OV_COMPUTE(2)                 // tile 62 (62%3==2)
  CBAR(0)                       // drain tile-63 batch
  OV_COMPUTE(0)                 // tile 63 (63%3==0)
  #undef OV_STAGE
  #undef OV_COMPUTE

  const int colb = n0 + wc * 64 + fr;
  const int rowb = m0 + wr * 32 + (ln >> 4) * 4;
  #pragma unroll
  for (int mi = 0; mi < 2; mi++)
    #pragma unroll
    for (int r = 0; r < 4; r++) {
      const int mr = rowb + mi * 16 + r;
      #pragma unroll
      for (int ni = 0; ni < 4; ni++)
        Cg[((long)bz << 20) + (long)mr * 512 + colb + ni * 16] = f2bf(acc[mi][ni][r]);
    }
}

// ---------------- fused theta/phi conv + G: one staging of x ---------------
// XCD map: L -> xcd = L&7, k = L>>3 (0..63). XCD i runs img-i x-slabs
// (k<32, all 32 px windows co-resident) then img-i y-slabs.
__global__ __launch_bounds__(512, 2)
void conv_ptg(const float* __restrict__ x, const float* __restrict__ y,
              const short* __restrict__ wth, const short* __restrict__ wph,
              const short* __restrict__ wg,
              const float* __restrict__ bth, const float* __restrict__ bph,
              const float* __restrict__ bg,
              short* __restrict__ TPT2, short* __restrict__ G)
{
  __shared__ __align__(16) short As[2][128 * 32];   // img [px][32c], swizzled
  __shared__ __align__(16) short Bs[2][256 * 32];   // wth/wph, swizzled
  __shared__ __align__(16) short Cs[2][256 * 32];   // wg, swizzled (x-blocks)
  const int L = blockIdx.x;
  const int xcd = L & 7, kk2 = L >> 3;              // kk2: 0..63
  const int slab = (kk2 >> 5) * 256 + xcd * 32 + (kk2 & 31);  // bijective
  const bool isphi = slab >= 256;
  const bool doG = !isphi;
  const int s2 = slab & 255;
  const int img = s2 >> 5;
  const float* src = (isphi ? y : x) + (long)img * (512L * 4096);
  const int px0 = (s2 & 31) * 128;
  const long m0 = (long)slab * 128;
  const short* W = isphi ? wph : wth;
  const float* bias = isphi ? bph : bth;
  const int t = threadIdx.x;
  const int wv = t >> 6, ln = t & 63;
  const int wpx = wv >> 2, wic = wv & 3;            // theta: [wpx*64 px][wic*64 ic]
  const int fr = ln & 15, q8 = (ln >> 4) * 8;
  const int g4 = (t >> 5) * 4, p4 = (t & 31) * 4;   // img stager coords
  const int w2 = wv - 4;                            // weight stager wave
  const int kcs = ((ln & 3) ^ (ln >> 4)) * 8;       // weight source swizzle

  f32x4 acc[4][4], accg[4][4];
  #pragma unroll
  for (int i = 0; i < 4; i++)
    #pragma unroll
    for (int j = 0; j < 4; j++)
      #pragma unroll
      for (int r = 0; r < 4; r++) { acc[i][j][r] = 0.f; accg[i][j][r] = 0.f; }

  // ---- prologue: fill buffer 0 (k-step 0)
  if (t >= 256) {
    #pragma unroll
    for (int j = 0; j < 4; j++)
      async_ld16(W + (long)(w2 * 64 + j * 16 + (ln >> 2)) * 512 + kcs,
                 &Bs[0][(w2 * 64 + j * 16) * 32]);
    if (doG) {
      #pragma unroll
      for (int j = 0; j < 4; j++)
        async_ld16(wg + (long)(w2 * 64 + j * 16 + (ln >> 2)) * 512 + kcs,
                   &Cs[0][(w2 * 64 + j * 16) * 32]);
    }
  } else {
    f32x4 r[4];
    #pragma unroll
    for (int i = 0; i < 4; i++)
      r[i] = *(const f32x4*)&src[(long)(g4 + i) * 4096 + px0 + p4];
    #pragma unroll
    for (int j = 0; j < 4; j++) {
      short4v w;
      w[0] = f2bf(r[0][j]); w[1] = f2bf(r[1][j]); w[2] = f2bf(r[2][j]); w[3] = f2bf(r[3][j]);
      const int px = p4 + j;
      const int u = (g4 >> 3) ^ ((px >> 2) & 3);
      *(short4v*)&As[0][px * 32 + u * 8 + (g4 & 4)] = w;
    }
  }
  __syncthreads();

  // ---- main loop: compute k-1 while staging k
  for (int k = 1; k < 16; k++) {
    const int cur = (k - 1) & 1, nxt = k & 1;
    f32x4 r[4];
    if (t >= 256) {
      #pragma unroll
      for (int j = 0; j < 4; j++)
        async_ld16(W + (long)(w2 * 64 + j * 16 + (ln >> 2)) * 512 + k * 32 + kcs,
                   &Bs[nxt][(w2 * 64 + j * 16) * 32]);
      if (doG) {
        #pragma unroll
        for (int j = 0; j < 4; j++)
          async_ld16(wg + (long)(w2 * 64 + j * 16 + (ln >> 2)) * 512 + k * 32 + kcs,
                     &Cs[nxt][(w2 * 64 + j * 16) * 32]);
      }
    } else {
      #pragma unroll
      for (int i = 0; i < 4; i++)
        r[i] = *(const f32x4*)&src[(long)(k * 32 + g4 + i) * 4096 + px0 + p4];
    }
    short8 af[4], bfv[4];
    #pragma unroll
    for (int mi = 0; mi < 4; mi++) af[mi] = frag_sw(&As[cur][0], wpx * 64 + mi * 16 + fr, q8);
    #pragma unroll
    for (int ni = 0; ni < 4; ni++) bfv[ni] = frag_sw(&Bs[cur][0], wic * 64 + ni * 16 + fr, q8);
    #pragma unroll
    for (int mi = 0; mi < 4; mi++)
      #pragma unroll
      for (int ni = 0; ni < 4; ni++)
        acc[mi][ni] = __builtin_amdgcn_mfma_f32_16x16x32_bf16(af[mi], bfv[ni], acc[mi][ni], 0, 0, 0);
    if (doG) {
      short8 ag[4], bg2[4];
      #pragma unroll
      for (int mi = 0; mi < 4; mi++) ag[mi] = frag_sw(&Cs[cur][0], wic * 64 + mi * 16 + fr, q8);
      #pragma unroll
      for (int ni = 0; ni < 4; ni++) bg2[ni] = frag_sw(&As[cur][0], wpx * 64 + ni * 16 + fr, q8);
      #pragma unroll
      for (int mi = 0; mi < 4; mi++)
        #pragma unroll
        for (int ni = 0; ni < 4; ni++)
          accg[mi][ni] = __builtin_amdgcn_mfma_f32_16x16x32_bf16(ag[mi], bg2[ni], accg[mi][ni], 0, 0, 0);
    }
    if (t < 256) {
      #pragma unroll
      for (int j = 0; j < 4; j++) {
        short4v w;
        w[0] = f2bf(r[0][j]); w[1] = f2bf(r[1][j]); w[2] = f2bf(r[2][j]); w[3] = f2bf(r[3][j]);
        const int px = p4 + j;
        const int u = (g4 >> 3) ^ ((px >> 2) & 3);
        *(short4v*)&As[nxt][px * 32 + u * 8 + (g4 & 4)] = w;
      }
    }
    __syncthreads();
  }

  // ---- final k-step (buffer 1)
  {
    short8 af[4], bfv[4];
    #pragma unroll
    for (int mi = 0; mi < 4; mi++) af[mi] = frag_sw(&As[1][0], wpx * 64 + mi * 16 + fr, q8);
    #pragma unroll
    for (int ni = 0; ni < 4; ni++) bfv[ni] = frag_sw(&Bs[1][0], wic * 64 + ni * 16 + fr, q8);
    #pragma unroll
    for (int mi = 0; mi < 4; mi++)
      #pragma unroll
      for (int ni = 0; ni < 4; ni++)
        acc[mi][ni] = __builtin_amdgcn_mfma_f32_16x16x32_bf16(af[mi], bfv[ni], acc[mi][ni], 0, 0, 0);
    if (doG) {
      short8 ag[4], bg2[4];
      #pragma unroll
      for (int mi = 0; mi < 4; mi++) ag[mi] = frag_sw(&Cs[1][0], wic * 64 + mi * 16 + fr, q8);
      #pragma unroll
      for (int ni = 0; ni < 4; ni++) bg2[ni] = frag_sw(&As[1][0], wpx * 64 + ni * 16 + fr, q8);
      #pragma unroll
      for (int mi = 0; mi < 4; mi++)
        #pragma unroll
        for (int ni = 0; ni < 4; ni++)
          accg[mi][ni] = __builtin_amdgcn_mfma_f32_16x16x32_bf16(ag[mi], bg2[ni], accg[mi][ni], 0, 0, 0);
    }
  }

  // ---- theta/phi epilogue
  const int colic = wic * 64 + fr;
  float cb[4];
  #pragma unroll
  for (int ni = 0; ni < 4; ni++) cb[ni] = bias[colic + ni * 16];
  #pragma unroll
  for (int mi = 0; mi < 4; mi++)
    #pragma unroll
    for (int r = 0; r < 4; r++) {
      const long m = m0 + wpx * 64 + mi * 16 + (ln >> 4) * 4 + r;
      #pragma unroll
      for (int ni = 0; ni < 4; ni++)
        TPT2[m * 256 + colic + ni * 16] = f2bf(acc[mi][ni][r] + cb[ni]);
    }

  // ---- G epilogue (x-blocks): G[ic][px] per image
  if (doG) {
    const int colpx = px0 + wpx * 64 + fr;
    #pragma unroll
    for (int mi = 0; mi < 4; mi++)
      #pragma unroll
      for (int r = 0; r < 4; r++) {
        const int ic = wic * 64 + mi * 16 + (ln >> 4) * 4 + r;
        const float badd = bg[ic];
        #pragma unroll
        for (int ni = 0; ni < 4; ni++)
          G[((long)img << 20) + (long)ic * 4096 + colpx + ni * 16] = f2bf(accg[mi][ni][r] + badd);
      }
  }
}

// ---------------- scores v3: 3-deep counted pipeline, XCD-colocated --------
__global__ __launch_bounds__(256)
void scores_k(const short* __restrict__ TT2, const short* __restrict__ PT2,
              short* __restrict__ ST, float* __restrict__ pstats)
{
  __shared__ __align__(16) short As[3][128 * 32];
  __shared__ __align__(16) short Bs[3][128 * 32];
  const int L = blockIdx.x;
  const int xcd = L & 7, kb = L >> 3;          // kb: 0..255
  const int grp = xcd * 16 + (kb >> 4);        // 0..127
  const int bz = grp >> 4, by = grp & 15, bx = kb & 15;
  const int t = threadIdx.x;
  const int wv = t >> 6, ln = t & 63;
  const int wm = (wv >> 1) * 64, wn = (wv & 1) * 64;
  const int fr = ln & 15, q8 = (ln >> 4) * 8;
  const int rowA = t >> 2;
  const int kcs = ((t & 3) ^ ((t >> 4) & 3)) * 8;

  const short* Abase = TT2 + ((long)(bz * 4096 + by * 128)) * 256;
  const short* Bbase = PT2 + ((long)(bz * 4096 + bx * 128)) * 256;

  f32x4 acc[4][4];
  #pragma unroll
  for (int i = 0; i < 4; i++)
    #pragma unroll
    for (int j = 0; j < 4; j++)
      #pragma unroll
      for (int r = 0; r < 4; r++) acc[i][j][r] = 0.f;

  #define SC_STAGE(s, buf)                                                     \
    {                                                                          \
      const long hoff = (long)((s) >> 3) * 2048 * 256;                         \
      const int kk = ((s) & 7) * 32;                                           \
      _Pragma("unroll")                                                        \
      for (int sv = 0; sv < 2; sv++) {                                         \
        async_ld16(Abase + hoff + (long)(sv * 64 + rowA) * 256 + kk + kcs,     \
                   &As[buf][0] + (sv * 256 + wv * 64) * 8);                    \
        async_ld16(Bbase + hoff + (long)(sv * 64 + rowA) * 256 + kk + kcs,     \
                   &Bs[buf][0] + (sv * 256 + wv * 64) * 8);                    \
      }                                                                        \
    }

  #define SC_COMPUTE(cbuf)                                                     \
    {                                                                          \
      const short* Ac = &As[cbuf][0];                                          \
      const short* Bc = &Bs[cbuf][0];                                          \
      short8 af[4], bfr[4];                                                    \
      _Pragma("unroll")                                                        \
      for (int mi = 0; mi < 4; mi++) af[mi] = frag_sw(Ac, wm + mi * 16 + fr, q8); \
      _Pragma("unroll")                                                        \
      for (int ni = 0; ni < 4; ni++) bfr[ni] = frag_sw(Bc, wn + ni * 16 + fr, q8); \
      _Pragma("unroll")                                                        \
      for (int mi = 0; mi < 4; mi++)                                           \
        _Pragma("unroll")                                                      \
        for (int ni = 0; ni < 4; ni++)                                         \
          acc[mi][ni] = __builtin_amdgcn_mfma_f32_16x16x32_bf16(               \
              af[mi], bfr[ni], acc[mi][ni], 0, 0, 0);                          \
    }

  SC_STAGE(0, 0);
  SC_STAGE(1, 1);
  CBAR(4)

  int cs = 0, ss = 2;
  for (int s = 0; s < 14; s++) {
    SC_STAGE(s + 2, ss);
    SC_COMPUTE(cs);
    CBAR(4)
    cs = (cs == 2) ? 0 : cs + 1;
    ss = (ss == 2) ? 0 : ss + 1;
  }
  SC_COMPUTE(2)                 // tile 14 (14%3==2)
  CBAR(0)
  SC_COMPUTE(0)                 // tile 15 (15%3==0)
  #undef SC_STAGE
  #undef SC_COMPUTE

  const int colb = bx * 128 + wn + fr;
  const int rowb = by * 128 + wm + (ln >> 4) * 4;
  short* base = ST + ((long)bz << 22);
  float ps[4] = {0.f, 0.f, 0.f, 0.f};
  #pragma unroll
  for (int mi = 0; mi < 4; mi++)
    #pragma unroll
    for (int r = 0; r < 4; r++) {
      const long mr = rowb + mi * 16 + r;
      #pragma unroll
      for (int ni = 0; ni < 4; ni++) {
        float e = __expf(acc[mi][ni][r]);
        base[mr * 2048 + colb + ni * 16] = f2bf(e);
        ps[ni] += e;
      }
    }
  #pragma unroll
  for (int ni = 0; ni < 4; ni++) {
    ps[ni] += __shfl_xor(ps[ni], 16);
    ps[ni] += __shfl_xor(ps[ni], 32);
  }
  float* part = (float*)&As[1][0];
  if (ln < 16) {
    #pragma unroll
    for (int ni = 0; ni < 4; ni++)
      part[(wv >> 1) * 128 + wn + ni * 16 + fr] = ps[ni];
  }
  __syncthreads();
  if (t < 128)
    pstats[((long)(bz * 16 + by)) * 2048 + bx * 128 + t] = part[t] + part[128 + t];
}

// ---------------- reduce 16 partials -> invZ per column --------------------
__global__ __launch_bounds__(256)
void zfinal(const float* __restrict__ pstats, float* __restrict__ invZ)
{
  const int g = blockIdx.x * 256 + threadIdx.x;
  const int b = g >> 11, col = g & 2047;
  float S = 0.f;
  #pragma unroll
  for (int rc = 0; rc < 16; rc++) S += pstats[((long)(b * 16 + rc)) * 2048 + col];
  invZ[g] = 1.f / S;
}

// ---------------- G *= invZ[m] (in place) ----------------------------------
__global__ __launch_bounds__(256)
void g_scale(short* __restrict__ G, const float* __restrict__ invZ)
{
  const long base = ((long)blockIdx.x * 256 + threadIdx.x) * 8;
  const int bz = (int)(base >> 20);
  const int n2 = (int)(base & 4095);
  const float* z = invZ + bz * 2048 + (n2 & 2047);
  short8 v = *(short8*)&G[base];
  f32x4 z0 = *(const f32x4*)z;
  f32x4 z1 = *(const f32x4*)(z + 4);
  #pragma unroll
  for (int j = 0; j < 4; j++) { v[j] = f2bf(bf2f(v[j]) * z0[j]); v[4 + j] = f2bf(bf2f(v[4 + j]) * z1[j]); }
  *(short8*)&G[base] = v;
}

// ---------------- mask GEMM v5: LDS-restaged row-major epilogue ------------
// K-loop identical to v4 (3-deep pipeline, XCD map). Epilogue: acc -> LDS
// (64-row halves, stride 132 f32) -> each thread handles f32x4 row-chunks:
// 512B-contiguous x reads and out writes (was 64B partial-line segments).
__global__ __launch_bounds__(256)
void mask_k(const short* __restrict__ Wm20, const short* __restrict__ Wm21,
            const short* __restrict__ OVT, const float* __restrict__ bmask,
            const float* __restrict__ x, float* __restrict__ out)
{
  __shared__ __align__(16) short As[3][128 * 32];
  __shared__ __align__(16) short Bs[3][128 * 32];
  const int L = blockIdx.x;
  const int xcd = L & 7, kb = L >> 3;          // kb: 0..127
  const int grp = xcd * 4 + (kb >> 5);         // 0..31
  const int bz = grp >> 2, by = grp & 3, bx = kb & 31;
  const int n0 = bx * 128;
  const int m0 = by * 128;
  const short* A = (n0 >= 2048) ? Wm21 : Wm20;
  const short* B = OVT + ((long)bz << 20) + (long)(n0 & 2047) * 512;
  const int t = threadIdx.x;
  const int wv = t >> 6, ln = t & 63;
  const int wm = (wv >> 1) * 64, wn = (wv & 1) * 64;
  const int fr = ln & 15, q8 = (ln >> 4) * 8;
  const int rowA = t >> 2;
  const int kcs = ((t & 3) ^ ((t >> 4) & 3)) * 8;

  f32x4 acc[4][4];
  #pragma unroll
  for (int i = 0; i < 4; i++)
    #pragma unroll
    for (int j = 0; j < 4; j++)
      #pragma unroll
      for (int r = 0; r < 4; r++) acc[i][j][r] = 0.f;

  #define MK_STAGE(s, buf)                                                     \
    {                                                                          \
      const int kk = (s) * 32;                                                 \
      _Pragma("unroll")                                                        \
      for (int sv = 0; sv < 2; sv++) {                                         \
        async_ld16(A + (long)(m0 + sv * 64 + rowA) * 512 + kk + kcs,           \
                   &As[buf][0] + (sv * 256 + wv * 64) * 8);                    \
        async_ld16(B + (long)(sv * 64 + rowA) * 512 + kk + kcs,                \
                   &Bs[buf][0] + (sv * 256 + wv * 64) * 8);                    \
      }                                                                        \
    }

  #define MK_COMPUTE(cbuf)                                                     \
    {                                                                          \
      const short* Ac = &As[cbuf][0];                                          \
      const short* Bc = &Bs[cbuf][0];                                          \
      short8 af[4], bfr[4];                                                    \
      _Pragma("unroll")                                                        \
      for (int mi = 0; mi < 4; mi++) af[mi] = frag_sw(Ac, wm + mi * 16 + fr, q8); \
      _Pragma("unroll")                                                        \
      for (int ni = 0; ni < 4; ni++) bfr[ni] = frag_sw(Bc, wn + ni * 16 + fr, q8); \
      _Pragma("unroll")                                                        \
      for (int mi = 0; mi < 4; mi++)                                           \
        _Pragma("unroll")                                                      \
        for (int ni = 0; ni < 4; ni++)                                         \
          acc[mi][ni] = __builtin_amdgcn_mfma_f32_16x16x32_bf16(               \
              af[mi], bfr[ni], acc[mi][ni], 0, 0, 0);                          \
    }

  MK_STAGE(0, 0);
  MK_STAGE(1, 1);
  CBAR(4)

  int cs = 0, ss = 2;
  for (int s = 0; s < 14; s++) {
    MK_STAGE(s + 2, ss);
    MK_COMPUTE(cs);
    CBAR(4)
    cs = (cs == 2) ? 0 : cs + 1;
    ss = (ss == 2) ? 0 : ss + 1;
  }
  MK_COMPUTE(2)                 // tile 14
  CBAR(0)
  MK_COMPUTE(0)                 // tile 15
  #undef MK_STAGE
  #undef MK_COMPUTE

  // ---- LDS-restaged epilogue: two 64-row halves ----
  // Waves 0,1 own rows 0-63 (wm=0); waves 2,3 own rows 64-127 (wm=64).
  float* Lf = (float*)&As[0][0];          // 64*132*4 = 33792B <= 49152B
  const long obase = ((long)bz * 512 + m0) * 4096 + n0;
  #pragma unroll
  for (int half = 0; half < 2; half++) {
    __syncthreads();                      // LDS free (K-loop / prev pass done)
    if ((wv >> 1) == half) {
      #pragma unroll
      for (int mi = 0; mi < 4; mi++)
        #pragma unroll
        for (int r = 0; r < 4; r++) {
          const int row = mi * 16 + (ln >> 4) * 4 + r;   // 0..63
          #pragma unroll
          for (int ni = 0; ni < 4; ni++)
            Lf[row * 132 + wn + ni * 16 + fr] = acc[mi][ni][r];
        }
    }
    __syncthreads();
    #pragma unroll
    for (int it = 0; it < 8; it++) {
      const int c = it * 256 + t;
      const int row = c >> 5;             // 0..63
      const int ch = c & 31;              // f32x4 chunk
      const int mr = m0 + half * 64 + row;
      const long go = obase + (long)(half * 64 + row) * 4096 + ch * 4;
      f32x4 xa = *(const f32x4*)&x[go];
      f32x4 la = *(const f32x4*)&Lf[row * 132 + ch * 4];
      const float badd = bmask[mr];
      f32x4 o;
      #pragma unroll
      for (int j = 0; j < 4; j++) o[j] = la[j] + badd + xa[j];
      *(f32x4*)&out[go] = o;
    }
  }
}

// ---------------- weight prep ----------------------------------------------
__global__ __launch_bounds__(256)
void wconv2(const float* w_phi, const float* w_theta, const float* w_g,
            const float* w_mask,
            short* wph, short* wth, short* wg, short* Wm20, short* Wm21)
{
  const int seg = blockIdx.x >> 6;
  const int blk = blockIdx.x & 63;
  const int i0 = blk * 2048 + threadIdx.x * 8;
  if (seg < 3) {
    const float* s = seg == 0 ? w_phi : seg == 1 ? w_theta : w_g;
    short* d = seg == 0 ? wph : seg == 1 ? wth : wg;
    f32x4 a = *(const f32x4*)&s[i0];
    f32x4 b = *(const f32x4*)&s[i0 + 4];
    short8 o;
    #pragma unroll
    for (int j = 0; j < 4; j++) { o[j] = f2bf(a[j]); o[4 + j] = f2bf(b[j]); }
    *(short8*)&d[i0] = o;
  } else {
    const int o = i0 >> 8;
    f32x4 a = *(const f32x4*)&w_mask[i0];
    f32x4 b = *(const f32x4*)&w_mask[i0 + 4];
    short v[8];
    #pragma unroll
    for (int j = 0; j < 4; j++) { v[j] = f2bf(a[j]); v[4 + j] = f2bf(b[j]); }
    short8 a0, a1, b0, b1;
    #pragma unroll
    for (int j = 0; j < 4; j++) {
      a0[2 * j] = v[j];     a0[2 * j + 1] = 0;
      a1[2 * j] = v[4 + j]; a1[2 * j + 1] = 0;
      b0[2 * j] = 0;        b0[2 * j + 1] = v[j];
      b1[2 * j] = 0;        b1[2 * j + 1] = v[4 + j];
    }
    const long base = (long)o * 512 + 2 * (i0 & 255);
    *(short8*)&Wm20[base] = a0; *(short8*)&Wm20[base + 8] = a1;
    *(short8*)&Wm21[base] = b0; *(short8*)&Wm21[base + 8] = b1;
  }
}

// ---------------------------------------------------------------------------
extern "C" void kernel_launch(void* const* d_in, const int* in_sizes, int n_in,
                              void* d_out, int out_size, void* d_ws, size_t ws_size,
                              hipStream_t stream)
{
  (void)in_sizes; (void)n_in; (void)out_size; (void)ws_size;
  const float* x       = (const float*)d_in[0];
  const float* y       = (const float*)d_in[1];
  const float* w_phi   = (const float*)d_in[2];
  const float* b_phi   = (const float*)d_in[3];
  const float* w_theta = (const float*)d_in[4];
  const float* b_theta = (const float*)d_in[5];
  const float* w_g     = (const float*)d_in[6];
  const float* b_g     = (const float*)d_in[7];
  const float* w_mask  = (const float*)d_in[8];
  const float* b_mask  = (const float*)d_in[9];
  float* out = (float*)d_out;

  char* ws = (char*)d_ws;
  const long MB = 1L << 20;
  short* wph  = (short*)(ws + 0);
  short* wth  = (short*)(ws + 256 * 1024);
  short* wg   = (short*)(ws + 512 * 1024);
  short* Wm20 = (short*)(ws + 768 * 1024);
  short* Wm21 = (short*)(ws + 1280 * 1024);
  short* TPT2 = (short*)(ws + 66 * MB);   // [65536][256], 32MB
  short* G    = (short*)(ws + 98 * MB);   // [8][256][4096], 16MB
  short* ST   = (short*)(ws + 2 * MB);    // [8][2048][2048] E, 64MB
  float* pstats = (float*)(ws + 114 * MB);
  float* invZ   = (float*)(ws + 115 * MB);
  short* OVT  = (short*)(ws + 66 * MB);   // [8][2048][512], 16MB (over TPT2)

  dim3 blk(256, 1, 1);
  dim3 blk8(512, 1, 1);

  wconv2<<<dim3(256, 1, 1), blk, 0, stream>>>(w_phi, w_theta, w_g, w_mask,
                                              wph, wth, wg, Wm20, Wm21);

  conv_ptg<<<dim3(512, 1, 1), blk8, 0, stream>>>(x, y, wth, wph, wg,
                                                 b_theta, b_phi, b_g, TPT2, G);

  scores_k<<<dim3(2048, 1, 1), blk, 0, stream>>>(TPT2, TPT2 + 32768L * 256, ST, pstats);
  zfinal<<<dim3(64, 1, 1), blk, 0, stream>>>(pstats, invZ);
  g_scale<<<dim3(4096, 1, 1), blk, 0, stream>>>(G, invZ);

  ov_k<<<dim3(512, 1, 1), blk8, 0, stream>>>(ST, G, OVT);

  mask_k<<<dim3(1024, 1, 1), blk, 0, stream>>>(Wm20, Wm21, OVT, b_mask, x, out);
}